// Round 10
// baseline (1008.132 us; speedup 1.0000x reference)
//
#include <hip/hip_runtime.h>
#include <math.h>
#include <stdint.h>

#define BB 8
#define SS 2048
#define D_IN 1024
#define D_OUTC 1024
#define LATC 256
#define NSTATE 32
#define DINNER 2048
#define DCONV 4
#define DTRANK 64
#define NCH 32   // colstats time-chunks

__device__ __forceinline__ float silu_f(float v) { return v * (1.f / (1.f + __expf(-v))); }
__device__ __forceinline__ float softplus_f(float v) {
    return fmaxf(v, 0.f) + log1pf(__expf(-fabsf(v)));
}

typedef short short8 __attribute__((ext_vector_type(8)));
typedef float f32x4 __attribute__((ext_vector_type(4)));

__device__ __forceinline__ unsigned short f2bf(float f) {
    unsigned u = __builtin_bit_cast(unsigned, f);
    u += 0x7FFFu + ((u >> 16) & 1u);          // round-to-nearest-even
    return (unsigned short)(u >> 16);
}
__device__ __forceinline__ int pack2(float a, float b) {
    return (int)((unsigned)f2bf(a) | ((unsigned)f2bf(b) << 16));
}

// async global->LDS, 16B per lane. LDS dest = wave-uniform base + lane*16.
typedef const __attribute__((address_space(1))) unsigned int* gas_ptr;
typedef __attribute__((address_space(3))) unsigned int* las_ptr;
__device__ __forceinline__ void gload16(const void* g, void* l) {
    __builtin_amdgcn_global_load_lds(
        reinterpret_cast<gas_ptr>(reinterpret_cast<uintptr_t>(g)),
        reinterpret_cast<las_ptr>(reinterpret_cast<uintptr_t>(l)),
        16, 0, 0);
}

// ---------------------------------------------------------------------------
// Tiled transpose + fp32->bf16 convert: src [K][N] fp32 -> dst [N][K] bf16.
// Optional batch via blockIdx.z with element strides zsrc/zdst.
// ---------------------------------------------------------------------------
__global__ __launch_bounds__(256) void transp_bf(const float* __restrict__ src,
                                                 unsigned short* __restrict__ dst,
                                                 int K, int N, long zsrc, long zdst)
{
    __shared__ float tile[32][33];
    src += (size_t)blockIdx.z * zsrc;
    dst += (size_t)blockIdx.z * zdst;
    const int n0 = blockIdx.x * 32;
    const int k0 = blockIdx.y * 32;
    const int x = threadIdx.x & 31;
    const int y = threadIdx.x >> 5;   // 0..7
#pragma unroll
    for (int j = 0; j < 4; j++)
        tile[y + 8 * j][x] = src[(size_t)(k0 + y + 8 * j) * N + n0 + x];
    __syncthreads();
#pragma unroll
    for (int j = 0; j < 4; j++)
        dst[(size_t)(n0 + y + 8 * j) * K + k0 + x] = f2bf(tile[x][y + 8 * j]);
}

// Tiled bf16 -> bf16 transpose: src [K][N] -> dst [N][K], batched via z.
__global__ __launch_bounds__(256) void transp16(const unsigned short* __restrict__ src,
                                                unsigned short* __restrict__ dst,
                                                int K, int N, long zsrc, long zdst)
{
    __shared__ unsigned short tile[32][33];
    src += (size_t)blockIdx.z * zsrc;
    dst += (size_t)blockIdx.z * zdst;
    const int n0 = blockIdx.x * 32;
    const int k0 = blockIdx.y * 32;
    const int x = threadIdx.x & 31;
    const int y = threadIdx.x >> 5;
#pragma unroll
    for (int j = 0; j < 4; j++)
        tile[y + 8 * j][x] = src[(size_t)(k0 + y + 8 * j) * N + n0 + x];
    __syncthreads();
#pragma unroll
    for (int j = 0; j < 4; j++)
        dst[(size_t)(n0 + y + 8 * j) * K + k0 + x] = tile[x][y + 8 * j];
}

// elementwise fp32 -> bf16 (8 elems/thread); n must be multiple of 2048
__global__ __launch_bounds__(256) void cvt_bf16(const float* __restrict__ in,
                                                unsigned short* __restrict__ out)
{
    size_t i = ((size_t)blockIdx.x * 256 + threadIdx.x) * 8;
    float4 a = *(const float4*)(in + i);
    float4 b = *(const float4*)(in + i + 4);
    int4 w;
    w.x = pack2(a.x, a.y); w.y = pack2(a.z, a.w);
    w.z = pack2(b.x, b.y); w.w = pack2(b.z, b.w);
    *(int4*)(out + i) = w;
}

// ---------------------------------------------------------------------------
// bf16 MFMA GEMM, async-staged + 2-phase double-buffered pipeline + XCD swizzle.
// ---------------------------------------------------------------------------
__global__ __launch_bounds__(256) void gemm16(
    const unsigned short* __restrict__ A, int lda,
    const unsigned short* __restrict__ BT, int ldb,
    const float* __restrict__ bias,
    float* __restrict__ C, int ldc,
    unsigned short* __restrict__ C16, int ldc16,
    int M, int N, int K, int act, int accum,
    int kspl, long zA, long zB, long zC, long zK)
{
    __shared__ __align__(16) unsigned short As[2][128 * 32];
    __shared__ __align__(16) unsigned short Bs[2][128 * 32];

    const int bz = blockIdx.z / kspl;
    const int ks = blockIdx.z % kspl;
    A += (size_t)bz * zA + (size_t)ks * (size_t)K;
    BT += (size_t)bz * zB + (size_t)ks * (size_t)K;
    if (C) C += (size_t)bz * zC + (size_t)ks * zK;

    const int tid = threadIdx.x;
    const int lane = tid & 63;
    const int wave = tid >> 6;   // 0..3
    const int wr = wave >> 1;    // wave row 0..1
    const int wc = wave & 1;     // wave col 0..1
    const int quad = lane >> 4;  // 0..3
    const int l16 = lane & 15;

    // XCD-aware bijective swizzle (T1, m204 formula) on the xy-plane
    const int nbx = gridDim.x;
    const int nwg = nbx * gridDim.y;
    const int orig = blockIdx.y * nbx + blockIdx.x;
    const int q = nwg >> 3, r = nwg & 7;
    const int xcd = orig & 7, lid = orig >> 3;
    const int swz = (xcd < r) ? (xcd * (q + 1) + lid)
                              : (r * (q + 1) + (xcd - r) * q + lid);
    const int m0 = (swz / nbx) * 128;
    const int n0 = (swz % nbx) * 128;

    const int srow4 = lane >> 2;   // 0..15
    const int sphys = lane & 3;    // physical 16B slot within 64B row

    f32x4 acc[4][4];
#pragma unroll
    for (int i = 0; i < 4; i++)
#pragma unroll
        for (int j = 0; j < 4; j++) acc[i][j] = (f32x4){0.f, 0.f, 0.f, 0.f};

    const int nt = K >> 5;

    auto STAGE = [&](int buf, int t) {
        const int k0 = t << 5;
#pragma unroll
        for (int i = 0; i < 2; i++) {
            const int rbase = (wave << 5) + (i << 4);
            const int rr = rbase + srow4;                       // 0..127
            const int ls = sphys ^ ((rr >> 1) & 3);             // logical slot
            gload16(A + (size_t)(m0 + rr) * lda + (k0 + (ls << 3)), &As[buf][rbase << 5]);
            gload16(BT + (size_t)(n0 + rr) * ldb + (k0 + (ls << 3)), &Bs[buf][rbase << 5]);
        }
    };

    // prologue: stage tile 0, drain, barrier
    STAGE(0, 0);
    asm volatile("s_waitcnt vmcnt(0)" ::: "memory");
    __syncthreads();

    int cur = 0;
    for (int t = 0; t < nt; ++t) {
        if (t + 1 < nt) STAGE(cur ^ 1, t + 1);

        short8 af[4], bfr[4];
#pragma unroll
        for (int i = 0; i < 4; i++) {
            const int ar = (wr << 6) + (i << 4) + l16;
            af[i] = *(const short8*)&As[cur][(ar << 5) + ((quad ^ ((ar >> 1) & 3)) << 3)];
            const int br = (wc << 6) + (i << 4) + l16;
            bfr[i] = *(const short8*)&Bs[cur][(br << 5) + ((quad ^ ((br >> 1) & 3)) << 3)];
        }
#pragma unroll
        for (int i = 0; i < 4; i++)
#pragma unroll
            for (int j = 0; j < 4; j++)
                acc[i][j] = __builtin_amdgcn_mfma_f32_16x16x32_bf16(af[i], bfr[j], acc[i][j], 0, 0, 0);

        asm volatile("s_waitcnt vmcnt(0)" ::: "memory");
        __syncthreads();
        cur ^= 1;
    }

    // epilogue: D mapping col = lane&15, row = quad*4 + reg
#pragma unroll
    for (int j = 0; j < 4; j++) {
        int gn = n0 + wc * 64 + j * 16 + l16;
        float bv = bias ? bias[gn] : 0.f;
#pragma unroll
        for (int i = 0; i < 4; i++) {
#pragma unroll
            for (int r2 = 0; r2 < 4; r2++) {
                int gm = m0 + wr * 64 + i * 16 + quad * 4 + r2;
                float v = acc[i][j][r2] + bv;
                if (act == 1) v = silu_f(v);
                else if (act == 2) v = softplus_f(v);
                if (C) {
                    size_t ci = (size_t)gm * ldc + gn;
                    if (accum) C[ci] += v;
                    else C[ci] = v;
                }
                if (C16) C16[(size_t)gm * ldc16 + gn] = f2bf(v);
            }
        }
    }
}

// ---------------------------------------------------------------------------
// fp32 SIMT GEMM (small / accuracy-sensitive GEMMs: x_proj, dt_proj)
// ---------------------------------------------------------------------------
__global__ __launch_bounds__(256) void gemm_kernel(
    const float* __restrict__ A, int lda, long strideA,
    const float* __restrict__ B, int ldb, long strideB,
    const float* __restrict__ bias,
    float* __restrict__ C, int ldc, long strideC,
    int M, int N, int K, int transA, int act, int accum)
{
    __shared__ float As[16][65];
    __shared__ float Bsh[16][64];

    const int bz = blockIdx.z;
    const float* Ab = A + (size_t)bz * strideA;
    const float* Bb = B + (size_t)bz * strideB;
    float* Cb = C + (size_t)bz * strideC;

    const int tx = threadIdx.x;
    const int ty = threadIdx.y;
    const int tid = ty * 16 + tx;
    const int m0 = blockIdx.y * 64;
    const int n0 = blockIdx.x * 64;

    float acc[4][4];
#pragma unroll
    for (int i = 0; i < 4; i++)
#pragma unroll
        for (int j = 0; j < 4; j++) acc[i][j] = 0.f;

    for (int k0 = 0; k0 < K; k0 += 16) {
        if (!transA) {
            int row = tid >> 2;
            int kc = (tid & 3) * 4;
            int gm = m0 + row;
#pragma unroll
            for (int j = 0; j < 4; j++) {
                int gk = k0 + kc + j;
                As[kc + j][row] = (gm < M && gk < K) ? Ab[(size_t)gm * lda + gk] : 0.f;
            }
        } else {
            int krow = tid >> 4;
            int mc = (tid & 15) * 4;
            int gk = k0 + krow;
#pragma unroll
            for (int j = 0; j < 4; j++) {
                int gm = m0 + mc + j;
                As[krow][mc + j] = (gm < M && gk < K) ? Ab[(size_t)gk * lda + gm] : 0.f;
            }
        }
        {
            int krow = tid >> 4;
            int nc = (tid & 15) * 4;
            int gk = k0 + krow;
#pragma unroll
            for (int j = 0; j < 4; j++) {
                int gn = n0 + nc + j;
                Bsh[krow][nc + j] = (gk < K && gn < N) ? Bb[(size_t)gk * ldb + gn] : 0.f;
            }
        }
        __syncthreads();
#pragma unroll
        for (int k = 0; k < 16; k++) {
            float a[4], bv[4];
#pragma unroll
            for (int i = 0; i < 4; i++) a[i] = As[k][ty * 4 + i];
#pragma unroll
            for (int j = 0; j < 4; j++) bv[j] = Bsh[k][tx * 4 + j];
#pragma unroll
            for (int i = 0; i < 4; i++)
#pragma unroll
                for (int j = 0; j < 4; j++) acc[i][j] += a[i] * bv[j];
        }
        __syncthreads();
    }

#pragma unroll
    for (int i = 0; i < 4; i++) {
        int gm = m0 + ty * 4 + i;
        if (gm >= M) continue;
#pragma unroll
        for (int j = 0; j < 4; j++) {
            int gn = n0 + tx * 4 + j;
            if (gn >= N) continue;
            float v = acc[i][j];
            if (bias) v += bias[gn];
            if (act == 1) v = silu_f(v);
            else if (act == 2) v = softplus_f(v);
            size_t ci = (size_t)gm * ldc + gn;
            if (accum) Cb[ci] += v;
            else Cb[ci] = v;
        }
    }
}

// sum 4 split-K partials
__global__ __launch_bounds__(256) void merge4_kernel(const float* __restrict__ part,
                                                     float* __restrict__ out, int n)
{
    int i = blockIdx.x * 256 + threadIdx.x;
    out[i] = part[i] + part[i + n] + part[i + 2 * n] + part[i + 3 * n];
}

// sum 2 split-K partials
__global__ __launch_bounds__(256) void merge2_kernel(const float* __restrict__ part,
                                                     float* __restrict__ out, int n)
{
    int i = blockIdx.x * 256 + threadIdx.x;
    out[i] = part[i] + part[i + n];
}

// ---------------------------------------------------------------------------
// column softmax stats, 2-phase
// ---------------------------------------------------------------------------
__global__ __launch_bounds__(256) void colstats_part_kernel(const float* __restrict__ w,
                                                            float* __restrict__ part)
{
    int b = blockIdx.x / NCH;
    int ch = blockIdx.x % NCH;
    int l = threadIdx.x;
    const float* base = w + ((size_t)b * SS + (size_t)ch * (SS / NCH)) * LATC + l;
    float m = -1e30f, s = 0.f;
    for (int t = 0; t < SS / NCH; t++) {
        float v = base[(size_t)t * LATC];
        float nm = fmaxf(m, v);
        s = s * __expf(m - nm) + __expf(v - nm);
        m = nm;
    }
    float2* p = (float2*)part;
    p[(size_t)(b * LATC + l) * NCH + ch] = make_float2(m, s);
}

__global__ __launch_bounds__(256) void colstats_merge_kernel(const float* __restrict__ part,
                                                             float* __restrict__ colst)
{
    int idx = blockIdx.x * 256 + threadIdx.x;   // 0 .. BB*LATC-1
    const float2* p = (const float2*)part + (size_t)idx * NCH;
    float m = -1e30f, s = 0.f;
#pragma unroll 4
    for (int c = 0; c < NCH; c++) {
        float2 v = p[c];
        float nm = fmaxf(m, v.x);
        s = s * __expf(m - nm) + v.y * __expf(v.x - nm);
        m = nm;
    }
    colst[idx * 2] = m;
    colst[idx * 2 + 1] = s;
}

__global__ __launch_bounds__(256) void softmix_kernel(float* __restrict__ w,
                                                      const float* __restrict__ colst)
{
    int bs = blockIdx.x;
    int b = bs / SS;
    int l = threadIdx.x;
    float* row = w + (size_t)bs * LATC;
    float v = row[l];

    __shared__ float sm[256];
    sm[l] = v;
    __syncthreads();
    for (int st = 128; st > 0; st >>= 1) {
        if (l < st) sm[l] = fmaxf(sm[l], sm[l + st]);
        __syncthreads();
    }
    float rmax = sm[0];
    __syncthreads();
    float e = __expf(v - rmax);
    sm[l] = e;
    __syncthreads();
    for (int st = 128; st > 0; st >>= 1) {
        if (l < st) sm[l] += sm[l + st];
        __syncthreads();
    }
    float rsum = sm[0];

    float w1 = e / rsum * ((float)LATC / (float)SS);
    float cm = colst[(b * LATC + l) * 2];
    float cs = colst[(b * LATC + l) * 2 + 1];
    float w2 = __expf(v - cm) / cs;
    row[l] = 0.5f * (w1 + w2);
}

// RMSNorm, bf16 output (consumed only as GEMM-A)
__global__ __launch_bounds__(256) void rmsnorm_kernel(const float* __restrict__ x,
                                                      const float* __restrict__ gamma,
                                                      unsigned short* __restrict__ out)
{
    int row = blockIdx.x;
    const float* xr = x + (size_t)row * D_OUTC;
    float v[4];
    float ss = 0.f;
#pragma unroll
    for (int i = 0; i < 4; i++) {
        v[i] = xr[threadIdx.x + i * 256];
        ss += v[i] * v[i];
    }
#pragma unroll
    for (int off = 32; off >= 1; off >>= 1) ss += __shfl_xor(ss, off, 64);
    __shared__ float sred[4];
    int wave = threadIdx.x >> 6;
    if ((threadIdx.x & 63) == 0) sred[wave] = ss;
    __syncthreads();
    float tot = sred[0] + sred[1] + sred[2] + sred[3];
    float inv = 32.0f / fmaxf(sqrtf(tot), 1e-12f);
    unsigned short* outr = out + (size_t)row * D_OUTC;
#pragma unroll
    for (int i = 0; i < 4; i++) {
        int d = threadIdx.x + i * 256;
        outr[d] = f2bf(v[i] * inv * gamma[d]);
    }
}

__global__ __launch_bounds__(256) void conv_silu_kernel(const float* __restrict__ xz,
                                                        const float* __restrict__ cw,
                                                        const float* __restrict__ cb,
                                                        float* __restrict__ xh, int L)
{
    int idx = blockIdx.x * 256 + threadIdx.x;
    int c = idx % DINNER;
    int bl = idx / DINNER;
    int l = bl % L;
    int b = bl / L;
    float acc = cb[c];
#pragma unroll
    for (int j = 0; j < DCONV; j++) {
        int ls = l - (DCONV - 1) + j;
        if (ls >= 0)
            acc += xz[((size_t)(b * L + ls)) * (2 * DINNER) + c] * cw[c * DCONV + j];
    }
    xh[idx] = silu_f(acc);
}

// ---------------------------------------------------------------------------
// Chunked selective scan: L split into NCHS chunks for 4x block parallelism.
// Chunk propagator identity: prod_t exp(dt_t*A_n) = exp(A_n * sum_t dt_t),
// so cross-chunk hand-off needs only h_final per chunk + sum(dt) per chunk.
// Pass 1: local recurrence from h=0 (no outputs) -> h_final, sum(dt).
// Pass 2: serial prefix over the 4 chunks per (b,d,n); h_final -> h_in inplace.
// Pass 3: full scan per chunk seeded with h_in (same layout/pipeline as r9).
// ---------------------------------------------------------------------------
#define SCH 4
#define NCHS 4
#define CHL (LATC / NCHS)   // 64 steps per chunk

__global__ __launch_bounds__(256) void scan_prop(const float* __restrict__ dty,
                                                 const float* __restrict__ xh,
                                                 const float* __restrict__ xdbc,
                                                 const float* __restrict__ A_log,
                                                 float* __restrict__ hfin,
                                                 float* __restrict__ sdtb,
                                                 int L)
{
    const int t = threadIdx.x;
    const int g = t & 7;
    const int dloc = t >> 3;
    const int b = blockIdx.x >> 6;
    const int d = ((blockIdx.x & 63) << 5) + dloc;
    const int c = blockIdx.y;

    float4 Av = *(const float4*)(A_log + (size_t)d * NSTATE + g * 4);
    const float A0 = -__expf(Av.x), A1 = -__expf(Av.y), A2 = -__expf(Av.z), A3 = -__expf(Av.w);
    float h0 = 0.f, h1 = 0.f, h2 = 0.f, h3 = 0.f, sdt = 0.f;

    const float* pdt = dty + ((size_t)b * L + (size_t)c * CHL) * DINNER + d;
    const float* pxh = xh + ((size_t)b * L + (size_t)c * CHL) * DINNER + d;
    const float* pbc = xdbc + ((size_t)b * L + (size_t)c * CHL) * 128 + DTRANK + g * 4;

    float a_dt[SCH], a_x[SCH];
    float4 a_B[SCH];
    float n_dt[SCH], n_x[SCH];
    float4 n_B[SCH];

#pragma unroll
    for (int j = 0; j < SCH; j++) {
        a_dt[j] = pdt[(size_t)j * DINNER];
        a_x[j]  = pxh[(size_t)j * DINNER];
        a_B[j]  = *(const float4*)(pbc + (size_t)j * 128);
    }

    for (int l0 = 0; l0 < CHL; l0 += SCH) {
        const int lb = (l0 + SCH < CHL) ? (l0 + SCH) : l0;
#pragma unroll
        for (int j = 0; j < SCH; j++) {
            n_dt[j] = pdt[(size_t)(lb + j) * DINNER];
            n_x[j]  = pxh[(size_t)(lb + j) * DINNER];
            n_B[j]  = *(const float4*)(pbc + (size_t)(lb + j) * 128);
        }
#pragma unroll
        for (int j = 0; j < SCH; j++) {
            float dtv = a_dt[j];
            float dtx = dtv * a_x[j];
            sdt += dtv;
            float e0 = __expf(dtv * A0);
            float e1 = __expf(dtv * A1);
            float e2 = __expf(dtv * A2);
            float e3 = __expf(dtv * A3);
            h0 = e0 * h0 + dtx * a_B[j].x;
            h1 = e1 * h1 + dtx * a_B[j].y;
            h2 = e2 * h2 + dtx * a_B[j].z;
            h3 = e3 * h3 + dtx * a_B[j].w;
        }
#pragma unroll
        for (int j = 0; j < SCH; j++) {
            a_dt[j] = n_dt[j]; a_x[j] = n_x[j]; a_B[j] = n_B[j];
        }
    }

    float4 hv; hv.x = h0; hv.y = h1; hv.z = h2; hv.w = h3;
    *(float4*)(hfin + ((((size_t)b * NCHS + c) * DINNER + d) << 5) + g * 4) = hv;
    if (g == 0) sdtb[((size_t)b * NCHS + c) * DINNER + d] = sdt;
}

__global__ __launch_bounds__(256) void scan_mid(float* __restrict__ hfin,
                                                const float* __restrict__ sdtb,
                                                const float* __restrict__ A_log)
{
    int idx = blockIdx.x * 256 + threadIdx.x;   // (b, d, n): 8*2048*32
    int n = idx & 31;
    int d = (idx >> 5) & (DINNER - 1);
    int b = idx >> 16;
    float An = -__expf(A_log[(size_t)d * NSTATE + n]);
    float h = 0.f;
#pragma unroll
    for (int c = 0; c < NCHS; c++) {
        size_t slot = ((((size_t)b * NCHS + c) * DINNER + d) << 5) + n;
        float hf = hfin[slot];
        hfin[slot] = h;                       // becomes h_in for chunk c
        float S = sdtb[((size_t)b * NCHS + c) * DINNER + d];
        h = __expf(An * S) * h + hf;
    }
}

__global__ __launch_bounds__(256) void scan_kernel(const float* __restrict__ dty,
                                                   const float* __restrict__ xh,
                                                   const float* __restrict__ xz,
                                                   const float* __restrict__ xdbc,
                                                   const float* __restrict__ A_log,
                                                   const float* __restrict__ Dp,
                                                   const float* __restrict__ hin,
                                                   unsigned short* __restrict__ ybf,
                                                   int L)
{
    const int t = threadIdx.x;
    const int g = t & 7;          // state group: states g*4 .. g*4+3
    const int dloc = t >> 3;      // 0..31
    const int b = blockIdx.x >> 6;
    const int d = ((blockIdx.x & 63) << 5) + dloc;
    const int c = blockIdx.y;

    float4 Av = *(const float4*)(A_log + (size_t)d * NSTATE + g * 4);
    const float A0 = -__expf(Av.x), A1 = -__expf(Av.y), A2 = -__expf(Av.z), A3 = -__expf(Av.w);
    float4 hv = *(const float4*)(hin + ((((size_t)b * NCHS + c) * DINNER + d) << 5) + g * 4);
    float h0 = hv.x, h1 = hv.y, h2 = hv.z, h3 = hv.w;
    const float Dd = Dp[d];

    const float* pdt = dty + ((size_t)b * L + (size_t)c * CHL) * DINNER + d;
    const float* pxh = xh + ((size_t)b * L + (size_t)c * CHL) * DINNER + d;
    const float* pz  = xz + ((size_t)b * L + (size_t)c * CHL) * 2 * DINNER + DINNER + d;
    const float* pbc = xdbc + ((size_t)b * L + (size_t)c * CHL) * 128 + DTRANK + g * 4;
    unsigned short* pout = ybf + ((size_t)b * L + (size_t)c * CHL) * DINNER + d;

    float a_dt[SCH], a_x[SCH], a_z[SCH];
    float4 a_B[SCH], a_C[SCH];
    float n_dt[SCH], n_x[SCH], n_z[SCH];
    float4 n_B[SCH], n_C[SCH];

#pragma unroll
    for (int j = 0; j < SCH; j++) {
        a_dt[j] = pdt[(size_t)j * DINNER];
        a_x[j]  = pxh[(size_t)j * DINNER];
        a_z[j]  = pz[(size_t)j * 2 * DINNER];
        a_B[j]  = *(const float4*)(pbc + (size_t)j * 128);
        a_C[j]  = *(const float4*)(pbc + (size_t)j * 128 + NSTATE);
    }

    for (int l0 = 0; l0 < CHL; l0 += SCH) {
        const int lb = (l0 + SCH < CHL) ? (l0 + SCH) : l0;   // last chunk: dead reload
#pragma unroll
        for (int j = 0; j < SCH; j++) {
            n_dt[j] = pdt[(size_t)(lb + j) * DINNER];
            n_x[j]  = pxh[(size_t)(lb + j) * DINNER];
            n_z[j]  = pz[(size_t)(lb + j) * 2 * DINNER];
            n_B[j]  = *(const float4*)(pbc + (size_t)(lb + j) * 128);
            n_C[j]  = *(const float4*)(pbc + (size_t)(lb + j) * 128 + NSTATE);
        }
#pragma unroll
        for (int j = 0; j < SCH; j++) {
            float dtv = a_dt[j], xv = a_x[j], zv = a_z[j];
            float dtx = dtv * xv;
            float e0 = __expf(dtv * A0);
            float e1 = __expf(dtv * A1);
            float e2 = __expf(dtv * A2);
            float e3 = __expf(dtv * A3);
            h0 = e0 * h0 + dtx * a_B[j].x;
            h1 = e1 * h1 + dtx * a_B[j].y;
            h2 = e2 * h2 + dtx * a_B[j].z;
            h3 = e3 * h3 + dtx * a_B[j].w;
            float accv = h0 * a_C[j].x + h1 * a_C[j].y + h2 * a_C[j].z + h3 * a_C[j].w;
            accv += __shfl_xor(accv, 1, 64);
            accv += __shfl_xor(accv, 2, 64);
            accv += __shfl_xor(accv, 4, 64);
            if (g == 0) {
                float yv = (accv + Dd * xv) * silu_f(zv);
                pout[(size_t)(l0 + j) * DINNER] = f2bf(yv);
            }
        }
#pragma unroll
        for (int j = 0; j < SCH; j++) {
            a_dt[j] = n_dt[j]; a_x[j] = n_x[j]; a_z[j] = n_z[j];
            a_B[j] = n_B[j];   a_C[j] = n_C[j];
        }
    }
}

// ---------------------------------------------------------------------------

extern "C" void kernel_launch(void* const* d_in, const int* in_sizes, int n_in,
                              void* d_out, int out_size, void* d_ws, size_t ws_size,
                              hipStream_t stream)
{
    const float* x      = (const float*)d_in[0];
    const float* W_in   = (const float*)d_in[1];
    const float* b_in   = (const float*)d_in[2];
    const float* Wa1    = (const float*)d_in[3];
    const float* ba1    = (const float*)d_in[4];
    const float* Wa2    = (const float*)d_in[5];
    const float* ba2    = (const float*)d_in[6];
    const float* gamma  = (const float*)d_in[7];
    const float* in_w   = (const float*)d_in[8];
    const float* conv_w = (const float*)d_in[9];
    const float* conv_b = (const float*)d_in[10];
    const float* x_w    = (const float*)d_in[11];
    const float* dt_w   = (const float*)d_in[12];
    const float* dt_b   = (const float*)d_in[13];
    const float* A_log  = (const float*)d_in[14];
    const float* Dp     = (const float*)d_in[15];
    const float* out_w  = (const float*)d_in[16];
    float* latout = (float*)d_out;

    char* wsb = (char*)d_ws;
    const size_t MB = 1 << 20;

    // ---- phase A layout ----
    unsigned short* out0_bf = (unsigned short*)(wsb);             // 32MB [0,32)
    unsigned short* xbf     = (unsigned short*)(wsb + 32 * MB);   // 32MB [32,64)
    float*          wbuf    = (float*)(wsb + 64 * MB);            // 16MB [64,80)
    unsigned short* t1_bf   = (unsigned short*)(wsb + 80 * MB);   //  8MB [80,88)
    unsigned short* WinT    = (unsigned short*)(wsb + 88 * MB);   //  2MB
    unsigned short* Wa1T    = (unsigned short*)(wsb + 90 * MB);   // .5MB
    unsigned short* Wa2T    = (unsigned short*)(wsb + 90 * MB + 512 * 1024);
    float*          cs_part = (float*)(wsb + 91 * MB);            //  2MB
    float*          colst   = (float*)(wsb + 95 * MB);            // 16KB

    // step-6 scratch (reuses dead phase-A regions; all < 95MB high-water)
    unsigned short* out0T   = (unsigned short*)(wsb + 32 * MB);   // 32MB (xbf dead)
    unsigned short* wT      = (unsigned short*)(wsb + 80 * MB);   //  8MB (t1_bf dead)
    float*          part6   = (float*)(wsb + 64 * MB);            // 16MB (wbuf dead after wT)

    // ---- phase B layout ----
    unsigned short* unorm_bf  = (unsigned short*)(wsb);           //  4MB [0,4)
    float*          xdbc_part = (float*)(wsb + 4 * MB);           //  4MB [4,8)
    float*          dtbuf     = (float*)(wsb + 8 * MB);           // 16MB [8,24)
    unsigned short* ybf       = (unsigned short*)(wsb + 24 * MB); //  8MB [24,32)
    float*          xz        = (float*)(wsb + 32 * MB);          // 32MB [32,64)
    float*          xh        = (float*)(wsb + 64 * MB);          // 16MB [64,80)
    unsigned short* wprojT    = (unsigned short*)(wsb + 80 * MB); //  8MB [80,88)
    unsigned short* oprojT    = (unsigned short*)(wsb + 88 * MB); //  4MB [88,92)
    float*          xdbc      = (float*)(wsb + 92 * MB);          //  1MB [92,93)
    // scan scratch (live only during step f; regions dead by then)
    float*          hfin      = (float*)(wsb + 80 * MB);          //  8MB (wprojT dead after b)
    float*          sdtb      = (float*)(wsb);                    // 256KB (unorm_bf dead after b)

    dim3 blk(16, 16);
    const int L = LATC;
    const int M1 = BB * SS;   // 16384
    const int ML = BB * L;    // 2048

    // 0) convert x -> bf16; transpose weights -> bf16 [N][K]
    cvt_bf16<<<dim3((size_t)M1 * D_IN / 2048), dim3(256), 0, stream>>>(x, xbf);
    transp_bf<<<dim3(D_OUTC / 32, D_IN / 32), dim3(256), 0, stream>>>(W_in, WinT, D_IN, D_OUTC, 0, 0);
    transp_bf<<<dim3(LATC / 32, D_OUTC / 32), dim3(256), 0, stream>>>(Wa1, Wa1T, D_OUTC, LATC, 0, 0);
    transp_bf<<<dim3(LATC / 32, LATC / 32), dim3(256), 0, stream>>>(Wa2, Wa2T, LATC, LATC, 0, 0);

    // 1) out0_bf = x @ W_in + b_in   (bf16 out only)
    gemm16<<<dim3(D_OUTC / 128, M1 / 128), dim3(256), 0, stream>>>(
        xbf, D_IN, WinT, D_IN, b_in, (float*)nullptr, 0, out0_bf, D_OUTC,
        M1, D_OUTC, D_IN, 0, 0, 1, 0, 0, 0, 0);

    // 2) t1_bf = silu(out0 @ Wa1 + ba1)
    gemm16<<<dim3(LATC / 128, M1 / 128), dim3(256), 0, stream>>>(
        out0_bf, D_OUTC, Wa1T, D_OUTC, ba1, (float*)nullptr, 0, t1_bf, LATC,
        M1, LATC, D_OUTC, 1, 0, 1, 0, 0, 0, 0);

    // 3) wbuf = t1 @ Wa2 + ba2   (fp32 out for softmax path)
    gemm16<<<dim3(LATC / 128, M1 / 128), dim3(256), 0, stream>>>(
        t1_bf, LATC, Wa2T, LATC, ba2, wbuf, LATC, (unsigned short*)nullptr, 0,
        M1, LATC, LATC, 0, 0, 1, 0, 0, 0, 0);

    // 4/5) softmax mix
    colstats_part_kernel<<<dim3(BB * NCH), dim3(256), 0, stream>>>(wbuf, cs_part);
    colstats_merge_kernel<<<dim3(BB * LATC / 256), dim3(256), 0, stream>>>(cs_part, colst);
    softmix_kernel<<<dim3(BB * SS), dim3(256), 0, stream>>>(wbuf, colst);

    // 6) latout[b] = weights[b]^T @ out0[b] — transposes + split-K=2 gemm16 + merge
    transp16<<<dim3(D_OUTC / 32, SS / 32, BB), dim3(256), 0, stream>>>(
        out0_bf, out0T, SS, D_OUTC, (long)SS * D_OUTC, (long)D_OUTC * SS);
    transp_bf<<<dim3(LATC / 32, SS / 32, BB), dim3(256), 0, stream>>>(
        wbuf, wT, SS, LATC, (long)SS * LATC, (long)LATC * SS);
    gemm16<<<dim3(D_OUTC / 128, LATC / 128, BB * 2), dim3(256), 0, stream>>>(
        wT, SS, out0T, SS, (const float*)nullptr,
        part6, D_OUTC, (unsigned short*)nullptr, 0,
        LATC, D_OUTC, SS / 2, 0, 0,
        2, (long)LATC * SS, (long)D_OUTC * SS, (long)LATC * D_OUTC,
        (long)BB * LATC * D_OUTC);
    merge2_kernel<<<dim3(BB * LATC * D_OUTC / 256), dim3(256), 0, stream>>>(
        part6, latout, BB * LATC * D_OUTC);

    // 7) two mamba blocks
    for (int i = 0; i < 2; i++) {
        const float* in_wi = in_w + (size_t)i * D_OUTC * 2 * DINNER;
        const float* cwi = conv_w + (size_t)i * DINNER * DCONV;
        const float* cbi = conv_b + (size_t)i * DINNER;
        const float* xwi = x_w + (size_t)i * DINNER * (DTRANK + 2 * NSTATE);
        const float* dtwi = dt_w + (size_t)i * DTRANK * DINNER;
        const float* dtbi = dt_b + (size_t)i * DINNER;
        const float* Ali = A_log + (size_t)i * DINNER * NSTATE;
        const float* Dpi = Dp + (size_t)i * DINNER;
        const float* owi = out_w + (size_t)i * DINNER * D_OUTC;
        const float* gi = gamma + (size_t)i * D_OUTC;

        // weight transposes for this block
        transp_bf<<<dim3(2 * DINNER / 32, D_OUTC / 32), dim3(256), 0, stream>>>(
            in_wi, wprojT, D_OUTC, 2 * DINNER, 0, 0);
        transp_bf<<<dim3(D_OUTC / 32, DINNER / 32), dim3(256), 0, stream>>>(
            owi, oprojT, DINNER, D_OUTC, 0, 0);

        // a) RMSNorm (bf16 out)
        rmsnorm_kernel<<<dim3(ML), dim3(256), 0, stream>>>(latout, gi, unorm_bf);

        // b) xz = unorm @ in_proj_w[i]   [2048,4096,1024]  (fp32 out)
        gemm16<<<dim3(2 * DINNER / 128, ML / 128), dim3(256), 0, stream>>>(
            unorm_bf, D_OUTC, wprojT, D_OUTC, (const float*)nullptr,
            xz, 2 * DINNER, (unsigned short*)nullptr, 0,
            ML, 2 * DINNER, D_OUTC, 0, 0, 1, 0, 0, 0, 0);

        // c) xh = silu(causal_conv(xz[:, :DINNER]) + cb)
        conv_silu_kernel<<<dim3(BB * L * DINNER / 256), dim3(256), 0, stream>>>(xz, cwi, cbi, xh, L);

        // d) xdbc = xh @ x_proj_w[i]   (fp32, split-K x4)
        gemm_kernel<<<dim3(128 / 64, ML / 64, 4), blk, 0, stream>>>(
            xh, DINNER, 512, xwi, 128, (long)512 * 128, (const float*)nullptr,
            xdbc_part, 128, (long)ML * 128, ML, 128, 512, 0, 0, 0);
        merge4_kernel<<<dim3(ML * 128 / 256), dim3(256), 0, stream>>>(
            xdbc_part, xdbc, ML * 128);

        // e) dt = softplus(xdbc[:, :64] @ dt_proj_w[i] + dt_b[i])  (fp32)
        gemm_kernel<<<dim3(DINNER / 64, ML / 64, 1), blk, 0, stream>>>(
            xdbc, 128, 0, dtwi, DINNER, 0, dtbi, dtbuf, DINNER, 0, ML, DINNER, DTRANK, 0, 2, 0);

        // f) chunked selective scan: prop -> prefix -> per-chunk scan (4x blocks)
        scan_prop<<<dim3(BB * 64, NCHS), dim3(256), 0, stream>>>(
            dtbuf, xh, xdbc, Ali, hfin, sdtb, L);
        scan_mid<<<dim3(BB * DINNER * NSTATE / 256), dim3(256), 0, stream>>>(
            hfin, sdtb, Ali);
        scan_kernel<<<dim3(BB * 64, NCHS), dim3(256), 0, stream>>>(
            dtbuf, xh, xz, xdbc, Ali, Dpi, hfin, ybf, L);

        // g) latout += y @ out_proj_w[i]
        gemm16<<<dim3(D_OUTC / 128, ML / 128), dim3(256), 0, stream>>>(
            ybf, DINNER, oprojT, DINNER, (const float*)nullptr,
            latout, D_OUTC, (unsigned short*)nullptr, 0,
            ML, D_OUTC, DINNER, 0, 1, 1, 0, 0, 0, 0);
    }
}

// Round 11
// 990.034 us; speedup vs baseline: 1.0183x; 1.0183x over previous
//
#include <hip/hip_runtime.h>
#include <math.h>
#include <stdint.h>

#define BB 8
#define SS 2048
#define D_IN 1024
#define D_OUTC 1024
#define LATC 256
#define NSTATE 32
#define DINNER 2048
#define DCONV 4
#define DTRANK 64
#define NCH 32   // colstats time-chunks

__device__ __forceinline__ float silu_f(float v) { return v * (1.f / (1.f + __expf(-v))); }
__device__ __forceinline__ float softplus_f(float v) {
    return fmaxf(v, 0.f) + log1pf(__expf(-fabsf(v)));
}

typedef short short8 __attribute__((ext_vector_type(8)));
typedef float f32x4 __attribute__((ext_vector_type(4)));

__device__ __forceinline__ unsigned short f2bf(float f) {
    unsigned u = __builtin_bit_cast(unsigned, f);
    u += 0x7FFFu + ((u >> 16) & 1u);          // round-to-nearest-even
    return (unsigned short)(u >> 16);
}
__device__ __forceinline__ int pack2(float a, float b) {
    return (int)((unsigned)f2bf(a) | ((unsigned)f2bf(b) << 16));
}

// async global->LDS, 16B per lane. LDS dest = wave-uniform base + lane*16.
typedef const __attribute__((address_space(1))) unsigned int* gas_ptr;
typedef __attribute__((address_space(3))) unsigned int* las_ptr;
__device__ __forceinline__ void gload16(const void* g, void* l) {
    __builtin_amdgcn_global_load_lds(
        reinterpret_cast<gas_ptr>(reinterpret_cast<uintptr_t>(g)),
        reinterpret_cast<las_ptr>(reinterpret_cast<uintptr_t>(l)),
        16, 0, 0);
}

// ---------------------------------------------------------------------------
// Tiled transpose + fp32->bf16 convert: src [K][N] fp32 -> dst [N][K] bf16.
// Optional batch via blockIdx.z with element strides zsrc/zdst.
// ---------------------------------------------------------------------------
__global__ __launch_bounds__(256) void transp_bf(const float* __restrict__ src,
                                                 unsigned short* __restrict__ dst,
                                                 int K, int N, long zsrc, long zdst)
{
    __shared__ float tile[32][33];
    src += (size_t)blockIdx.z * zsrc;
    dst += (size_t)blockIdx.z * zdst;
    const int n0 = blockIdx.x * 32;
    const int k0 = blockIdx.y * 32;
    const int x = threadIdx.x & 31;
    const int y = threadIdx.x >> 5;   // 0..7
#pragma unroll
    for (int j = 0; j < 4; j++)
        tile[y + 8 * j][x] = src[(size_t)(k0 + y + 8 * j) * N + n0 + x];
    __syncthreads();
#pragma unroll
    for (int j = 0; j < 4; j++)
        dst[(size_t)(n0 + y + 8 * j) * K + k0 + x] = f2bf(tile[x][y + 8 * j]);
}

// Tiled bf16 -> bf16 transpose: src [K][N] -> dst [N][K], batched via z.
__global__ __launch_bounds__(256) void transp16(const unsigned short* __restrict__ src,
                                                unsigned short* __restrict__ dst,
                                                int K, int N, long zsrc, long zdst)
{
    __shared__ unsigned short tile[32][33];
    src += (size_t)blockIdx.z * zsrc;
    dst += (size_t)blockIdx.z * zdst;
    const int n0 = blockIdx.x * 32;
    const int k0 = blockIdx.y * 32;
    const int x = threadIdx.x & 31;
    const int y = threadIdx.x >> 5;
#pragma unroll
    for (int j = 0; j < 4; j++)
        tile[y + 8 * j][x] = src[(size_t)(k0 + y + 8 * j) * N + n0 + x];
    __syncthreads();
#pragma unroll
    for (int j = 0; j < 4; j++)
        dst[(size_t)(n0 + y + 8 * j) * K + k0 + x] = tile[x][y + 8 * j];
}

// elementwise fp32 -> bf16 (8 elems/thread); n must be multiple of 2048
__global__ __launch_bounds__(256) void cvt_bf16(const float* __restrict__ in,
                                                unsigned short* __restrict__ out)
{
    size_t i = ((size_t)blockIdx.x * 256 + threadIdx.x) * 8;
    float4 a = *(const float4*)(in + i);
    float4 b = *(const float4*)(in + i + 4);
    int4 w;
    w.x = pack2(a.x, a.y); w.y = pack2(a.z, a.w);
    w.z = pack2(b.x, b.y); w.w = pack2(b.z, b.w);
    *(int4*)(out + i) = w;
}

// ---------------------------------------------------------------------------
// bf16 MFMA GEMM: async-staged, 3-buffer depth-2 pipeline with COUNTED vmcnt
// (T4: never drain to 0 mid-loop), XCD-bijective block swizzle.
//   C[M,N] = act(A @ B^T_layout + bias)   (C fp32 and/or C16 bf16, += option)
// A bf16 [M][K] row-major, BT bf16 [N][K] row-major.
// Per STAGE each thread issues 4 global_load_lds (A x2, B x2). With 2 stages
// in flight, wait vmcnt(4) = "newest stage may be outstanding, older landed"
// (in-order completion, m135). Tail: vmcnt(0). Per-wave wait + barrier =>
// block-wide LDS visibility. Buffer (t+2)%3 overwrites (t-1)%3 whose readers
// all passed the previous barrier.
// ---------------------------------------------------------------------------
__global__ __launch_bounds__(256) void gemm16(
    const unsigned short* __restrict__ A, int lda,
    const unsigned short* __restrict__ BT, int ldb,
    const float* __restrict__ bias,
    float* __restrict__ C, int ldc,
    unsigned short* __restrict__ C16, int ldc16,
    int M, int N, int K, int act, int accum,
    int kspl, long zA, long zB, long zC, long zK)
{
    __shared__ __align__(16) unsigned short As[3][128 * 32];
    __shared__ __align__(16) unsigned short Bs[3][128 * 32];

    const int bz = blockIdx.z / kspl;
    const int ks = blockIdx.z % kspl;
    A += (size_t)bz * zA + (size_t)ks * (size_t)K;
    BT += (size_t)bz * zB + (size_t)ks * (size_t)K;
    if (C) C += (size_t)bz * zC + (size_t)ks * zK;

    const int tid = threadIdx.x;
    const int lane = tid & 63;
    const int wave = tid >> 6;   // 0..3
    const int wr = wave >> 1;    // wave row 0..1
    const int wc = wave & 1;     // wave col 0..1
    const int quad = lane >> 4;  // 0..3
    const int l16 = lane & 15;

    // XCD-aware bijective swizzle (T1, m204 formula) on the xy-plane
    const int nbx = gridDim.x;
    const int nwg = nbx * gridDim.y;
    const int orig = blockIdx.y * nbx + blockIdx.x;
    const int q = nwg >> 3, r = nwg & 7;
    const int xcd = orig & 7, lid = orig >> 3;
    const int swz = (xcd < r) ? (xcd * (q + 1) + lid)
                              : (r * (q + 1) + (xcd - r) * q + lid);
    const int m0 = (swz / nbx) * 128;
    const int n0 = (swz % nbx) * 128;

    const int srow4 = lane >> 2;   // 0..15
    const int sphys = lane & 3;    // physical 16B slot within 64B row

    f32x4 acc[4][4];
#pragma unroll
    for (int i = 0; i < 4; i++)
#pragma unroll
        for (int j = 0; j < 4; j++) acc[i][j] = (f32x4){0.f, 0.f, 0.f, 0.f};

    const int nt = K >> 5;

    auto STAGE = [&](int buf, int t) {
        const int k0 = t << 5;
#pragma unroll
        for (int i = 0; i < 2; i++) {
            const int rbase = (wave << 5) + (i << 4);
            const int rr = rbase + srow4;                       // 0..127
            const int ls = sphys ^ ((rr >> 1) & 3);             // logical slot
            gload16(A + (size_t)(m0 + rr) * lda + (k0 + (ls << 3)), &As[buf][rbase << 5]);
            gload16(BT + (size_t)(n0 + rr) * ldb + (k0 + (ls << 3)), &Bs[buf][rbase << 5]);
        }
    };

    // prologue: stage tiles 0 and 1; wait for tile 0 only (counted)
    STAGE(0, 0);
    if (nt > 1) {
        STAGE(1, 1);
        asm volatile("s_waitcnt vmcnt(4)" ::: "memory");
    } else {
        asm volatile("s_waitcnt vmcnt(0)" ::: "memory");
    }
    __syncthreads();

    int cur = 0;
    for (int t = 0; t < nt; ++t) {
        // issue tile t+2 into buffer (t+2)%3 — two stages in flight
        int sb = cur + 2; if (sb >= 3) sb -= 3;
        if (t + 2 < nt) STAGE(sb, t + 2);

        short8 af[4], bfr[4];
#pragma unroll
        for (int i = 0; i < 4; i++) {
            const int ar = (wr << 6) + (i << 4) + l16;
            af[i] = *(const short8*)&As[cur][(ar << 5) + ((quad ^ ((ar >> 1) & 3)) << 3)];
            const int br = (wc << 6) + (i << 4) + l16;
            bfr[i] = *(const short8*)&Bs[cur][(br << 5) + ((quad ^ ((br >> 1) & 3)) << 3)];
        }
#pragma unroll
        for (int i = 0; i < 4; i++)
#pragma unroll
            for (int j = 0; j < 4; j++)
                acc[i][j] = __builtin_amdgcn_mfma_f32_16x16x32_bf16(af[i], bfr[j], acc[i][j], 0, 0, 0);

        // need tile t+1 landed before next iter; newest stage (t+2) may fly
        if (t + 2 < nt) asm volatile("s_waitcnt vmcnt(4)" ::: "memory");
        else            asm volatile("s_waitcnt vmcnt(0)" ::: "memory");
        __syncthreads();
        cur = (cur == 2) ? 0 : cur + 1;
    }

    // epilogue: D mapping col = lane&15, row = quad*4 + reg
#pragma unroll
    for (int j = 0; j < 4; j++) {
        int gn = n0 + wc * 64 + j * 16 + l16;
        float bv = bias ? bias[gn] : 0.f;
#pragma unroll
        for (int i = 0; i < 4; i++) {
#pragma unroll
            for (int r2 = 0; r2 < 4; r2++) {
                int gm = m0 + wr * 64 + i * 16 + quad * 4 + r2;
                float v = acc[i][j][r2] + bv;
                if (act == 1) v = silu_f(v);
                else if (act == 2) v = softplus_f(v);
                if (C) {
                    size_t ci = (size_t)gm * ldc + gn;
                    if (accum) C[ci] += v;
                    else C[ci] = v;
                }
                if (C16) C16[(size_t)gm * ldc16 + gn] = f2bf(v);
            }
        }
    }
}

// ---------------------------------------------------------------------------
// fp32 SIMT GEMM (small / accuracy-sensitive GEMMs: x_proj, dt_proj)
// ---------------------------------------------------------------------------
__global__ __launch_bounds__(256) void gemm_kernel(
    const float* __restrict__ A, int lda, long strideA,
    const float* __restrict__ B, int ldb, long strideB,
    const float* __restrict__ bias,
    float* __restrict__ C, int ldc, long strideC,
    int M, int N, int K, int transA, int act, int accum)
{
    __shared__ float As[16][65];
    __shared__ float Bsh[16][64];

    const int bz = blockIdx.z;
    const float* Ab = A + (size_t)bz * strideA;
    const float* Bb = B + (size_t)bz * strideB;
    float* Cb = C + (size_t)bz * strideC;

    const int tx = threadIdx.x;
    const int ty = threadIdx.y;
    const int tid = ty * 16 + tx;
    const int m0 = blockIdx.y * 64;
    const int n0 = blockIdx.x * 64;

    float acc[4][4];
#pragma unroll
    for (int i = 0; i < 4; i++)
#pragma unroll
        for (int j = 0; j < 4; j++) acc[i][j] = 0.f;

    for (int k0 = 0; k0 < K; k0 += 16) {
        if (!transA) {
            int row = tid >> 2;
            int kc = (tid & 3) * 4;
            int gm = m0 + row;
#pragma unroll
            for (int j = 0; j < 4; j++) {
                int gk = k0 + kc + j;
                As[kc + j][row] = (gm < M && gk < K) ? Ab[(size_t)gm * lda + gk] : 0.f;
            }
        } else {
            int krow = tid >> 4;
            int mc = (tid & 15) * 4;
            int gk = k0 + krow;
#pragma unroll
            for (int j = 0; j < 4; j++) {
                int gm = m0 + mc + j;
                As[krow][mc + j] = (gm < M && gk < K) ? Ab[(size_t)gk * lda + gm] : 0.f;
            }
        }
        {
            int krow = tid >> 4;
            int nc = (tid & 15) * 4;
            int gk = k0 + krow;
#pragma unroll
            for (int j = 0; j < 4; j++) {
                int gn = n0 + nc + j;
                Bsh[krow][nc + j] = (gk < K && gn < N) ? Bb[(size_t)gk * ldb + gn] : 0.f;
            }
        }
        __syncthreads();
#pragma unroll
        for (int k = 0; k < 16; k++) {
            float a[4], bv[4];
#pragma unroll
            for (int i = 0; i < 4; i++) a[i] = As[k][ty * 4 + i];
#pragma unroll
            for (int j = 0; j < 4; j++) bv[j] = Bsh[k][tx * 4 + j];
#pragma unroll
            for (int i = 0; i < 4; i++)
#pragma unroll
                for (int j = 0; j < 4; j++) acc[i][j] += a[i] * bv[j];
        }
        __syncthreads();
    }

#pragma unroll
    for (int i = 0; i < 4; i++) {
        int gm = m0 + ty * 4 + i;
        if (gm >= M) continue;
#pragma unroll
        for (int j = 0; j < 4; j++) {
            int gn = n0 + tx * 4 + j;
            if (gn >= N) continue;
            float v = acc[i][j];
            if (bias) v += bias[gn];
            if (act == 1) v = silu_f(v);
            else if (act == 2) v = softplus_f(v);
            size_t ci = (size_t)gm * ldc + gn;
            if (accum) Cb[ci] += v;
            else Cb[ci] = v;
        }
    }
}

// sum 4 split-K partials
__global__ __launch_bounds__(256) void merge4_kernel(const float* __restrict__ part,
                                                     float* __restrict__ out, int n)
{
    int i = blockIdx.x * 256 + threadIdx.x;
    out[i] = part[i] + part[i + n] + part[i + 2 * n] + part[i + 3 * n];
}

// sum 2 split-K partials
__global__ __launch_bounds__(256) void merge2_kernel(const float* __restrict__ part,
                                                     float* __restrict__ out, int n)
{
    int i = blockIdx.x * 256 + threadIdx.x;
    out[i] = part[i] + part[i + n];
}

// ---------------------------------------------------------------------------
// column softmax stats, 2-phase
// ---------------------------------------------------------------------------
__global__ __launch_bounds__(256) void colstats_part_kernel(const float* __restrict__ w,
                                                            float* __restrict__ part)
{
    int b = blockIdx.x / NCH;
    int ch = blockIdx.x % NCH;
    int l = threadIdx.x;
    const float* base = w + ((size_t)b * SS + (size_t)ch * (SS / NCH)) * LATC + l;
    float m = -1e30f, s = 0.f;
    for (int t = 0; t < SS / NCH; t++) {
        float v = base[(size_t)t * LATC];
        float nm = fmaxf(m, v);
        s = s * __expf(m - nm) + __expf(v - nm);
        m = nm;
    }
    float2* p = (float2*)part;
    p[(size_t)(b * LATC + l) * NCH + ch] = make_float2(m, s);
}

__global__ __launch_bounds__(256) void colstats_merge_kernel(const float* __restrict__ part,
                                                             float* __restrict__ colst)
{
    int idx = blockIdx.x * 256 + threadIdx.x;   // 0 .. BB*LATC-1
    const float2* p = (const float2*)part + (size_t)idx * NCH;
    float m = -1e30f, s = 0.f;
#pragma unroll 4
    for (int c = 0; c < NCH; c++) {
        float2 v = p[c];
        float nm = fmaxf(m, v.x);
        s = s * __expf(m - nm) + v.y * __expf(v.x - nm);
        m = nm;
    }
    colst[idx * 2] = m;
    colst[idx * 2 + 1] = s;
}

__global__ __launch_bounds__(256) void softmix_kernel(float* __restrict__ w,
                                                      const float* __restrict__ colst)
{
    int bs = blockIdx.x;
    int b = bs / SS;
    int l = threadIdx.x;
    float* row = w + (size_t)bs * LATC;
    float v = row[l];

    __shared__ float sm[256];
    sm[l] = v;
    __syncthreads();
    for (int st = 128; st > 0; st >>= 1) {
        if (l < st) sm[l] = fmaxf(sm[l], sm[l + st]);
        __syncthreads();
    }
    float rmax = sm[0];
    __syncthreads();
    float e = __expf(v - rmax);
    sm[l] = e;
    __syncthreads();
    for (int st = 128; st > 0; st >>= 1) {
        if (l < st) sm[l] += sm[l + st];
        __syncthreads();
    }
    float rsum = sm[0];

    float w1 = e / rsum * ((float)LATC / (float)SS);
    float cm = colst[(b * LATC + l) * 2];
    float cs = colst[(b * LATC + l) * 2 + 1];
    float w2 = __expf(v - cm) / cs;
    row[l] = 0.5f * (w1 + w2);
}

// RMSNorm, bf16 output (consumed only as GEMM-A)
__global__ __launch_bounds__(256) void rmsnorm_kernel(const float* __restrict__ x,
                                                      const float* __restrict__ gamma,
                                                      unsigned short* __restrict__ out)
{
    int row = blockIdx.x;
    const float* xr = x + (size_t)row * D_OUTC;
    float v[4];
    float ss = 0.f;
#pragma unroll
    for (int i = 0; i < 4; i++) {
        v[i] = xr[threadIdx.x + i * 256];
        ss += v[i] * v[i];
    }
#pragma unroll
    for (int off = 32; off >= 1; off >>= 1) ss += __shfl_xor(ss, off, 64);
    __shared__ float sred[4];
    int wave = threadIdx.x >> 6;
    if ((threadIdx.x & 63) == 0) sred[wave] = ss;
    __syncthreads();
    float tot = sred[0] + sred[1] + sred[2] + sred[3];
    float inv = 32.0f / fmaxf(sqrtf(tot), 1e-12f);
    unsigned short* outr = out + (size_t)row * D_OUTC;
#pragma unroll
    for (int i = 0; i < 4; i++) {
        int d = threadIdx.x + i * 256;
        outr[d] = f2bf(v[i] * inv * gamma[d]);
    }
}

__global__ __launch_bounds__(256) void conv_silu_kernel(const float* __restrict__ xz,
                                                        const float* __restrict__ cw,
                                                        const float* __restrict__ cb,
                                                        float* __restrict__ xh, int L)
{
    int idx = blockIdx.x * 256 + threadIdx.x;
    int c = idx % DINNER;
    int bl = idx / DINNER;
    int l = bl % L;
    int b = bl / L;
    float acc = cb[c];
#pragma unroll
    for (int j = 0; j < DCONV; j++) {
        int ls = l - (DCONV - 1) + j;
        if (ls >= 0)
            acc += xz[((size_t)(b * L + ls)) * (2 * DINNER) + c] * cw[c * DCONV + j];
    }
    xh[idx] = silu_f(acc);
}

// ---------------------------------------------------------------------------
// selective scan, 8-way state-split + 4-deep input pipeline (round-9 version,
// measured 98us; the chunked 3-pass variant was a net wash and was reverted).
// ---------------------------------------------------------------------------
#define SCH 4
__global__ __launch_bounds__(256) void scan_kernel(const float* __restrict__ dty,
                                                   const float* __restrict__ xh,
                                                   const float* __restrict__ xz,
                                                   const float* __restrict__ xdbc,
                                                   const float* __restrict__ A_log,
                                                   const float* __restrict__ Dp,
                                                   unsigned short* __restrict__ ybf,
                                                   int L)
{
    const int t = threadIdx.x;
    const int g = t & 7;          // state group: states g*4 .. g*4+3
    const int dloc = t >> 3;      // 0..31
    const int b = blockIdx.x >> 6;
    const int d = ((blockIdx.x & 63) << 5) + dloc;

    float4 Av = *(const float4*)(A_log + (size_t)d * NSTATE + g * 4);
    const float A0 = -__expf(Av.x), A1 = -__expf(Av.y), A2 = -__expf(Av.z), A3 = -__expf(Av.w);
    float h0 = 0.f, h1 = 0.f, h2 = 0.f, h3 = 0.f;
    const float Dd = Dp[d];

    const float* pdt = dty + (size_t)b * L * DINNER + d;
    const float* pxh = xh + (size_t)b * L * DINNER + d;
    const float* pz  = xz + (size_t)b * L * 2 * DINNER + DINNER + d;
    const float* pbc = xdbc + (size_t)b * L * 128 + DTRANK + g * 4;
    unsigned short* pout = ybf + (size_t)b * L * DINNER + d;

    float a_dt[SCH], a_x[SCH], a_z[SCH];
    float4 a_B[SCH], a_C[SCH];
    float n_dt[SCH], n_x[SCH], n_z[SCH];
    float4 n_B[SCH], n_C[SCH];

#pragma unroll
    for (int j = 0; j < SCH; j++) {
        a_dt[j] = pdt[(size_t)j * DINNER];
        a_x[j]  = pxh[(size_t)j * DINNER];
        a_z[j]  = pz[(size_t)j * 2 * DINNER];
        a_B[j]  = *(const float4*)(pbc + (size_t)j * 128);
        a_C[j]  = *(const float4*)(pbc + (size_t)j * 128 + NSTATE);
    }

    for (int l0 = 0; l0 < L; l0 += SCH) {
        const int lb = (l0 + SCH < L) ? (l0 + SCH) : l0;   // last chunk: dead reload
#pragma unroll
        for (int j = 0; j < SCH; j++) {
            n_dt[j] = pdt[(size_t)(lb + j) * DINNER];
            n_x[j]  = pxh[(size_t)(lb + j) * DINNER];
            n_z[j]  = pz[(size_t)(lb + j) * 2 * DINNER];
            n_B[j]  = *(const float4*)(pbc + (size_t)(lb + j) * 128);
            n_C[j]  = *(const float4*)(pbc + (size_t)(lb + j) * 128 + NSTATE);
        }
#pragma unroll
        for (int j = 0; j < SCH; j++) {
            float dtv = a_dt[j], xv = a_x[j], zv = a_z[j];
            float dtx = dtv * xv;
            float e0 = __expf(dtv * A0);
            float e1 = __expf(dtv * A1);
            float e2 = __expf(dtv * A2);
            float e3 = __expf(dtv * A3);
            h0 = e0 * h0 + dtx * a_B[j].x;
            h1 = e1 * h1 + dtx * a_B[j].y;
            h2 = e2 * h2 + dtx * a_B[j].z;
            h3 = e3 * h3 + dtx * a_B[j].w;
            float accv = h0 * a_C[j].x + h1 * a_C[j].y + h2 * a_C[j].z + h3 * a_C[j].w;
            accv += __shfl_xor(accv, 1, 64);
            accv += __shfl_xor(accv, 2, 64);
            accv += __shfl_xor(accv, 4, 64);
            if (g == 0) {
                float yv = (accv + Dd * xv) * silu_f(zv);
                pout[(size_t)(l0 + j) * DINNER] = f2bf(yv);
            }
        }
#pragma unroll
        for (int j = 0; j < SCH; j++) {
            a_dt[j] = n_dt[j]; a_x[j] = n_x[j]; a_z[j] = n_z[j];
            a_B[j] = n_B[j];   a_C[j] = n_C[j];
        }
    }
}

// ---------------------------------------------------------------------------

extern "C" void kernel_launch(void* const* d_in, const int* in_sizes, int n_in,
                              void* d_out, int out_size, void* d_ws, size_t ws_size,
                              hipStream_t stream)
{
    const float* x      = (const float*)d_in[0];
    const float* W_in   = (const float*)d_in[1];
    const float* b_in   = (const float*)d_in[2];
    const float* Wa1    = (const float*)d_in[3];
    const float* ba1    = (const float*)d_in[4];
    const float* Wa2    = (const float*)d_in[5];
    const float* ba2    = (const float*)d_in[6];
    const float* gamma  = (const float*)d_in[7];
    const float* in_w   = (const float*)d_in[8];
    const float* conv_w = (const float*)d_in[9];
    const float* conv_b = (const float*)d_in[10];
    const float* x_w    = (const float*)d_in[11];
    const float* dt_w   = (const float*)d_in[12];
    const float* dt_b   = (const float*)d_in[13];
    const float* A_log  = (const float*)d_in[14];
    const float* Dp     = (const float*)d_in[15];
    const float* out_w  = (const float*)d_in[16];
    float* latout = (float*)d_out;

    char* wsb = (char*)d_ws;
    const size_t MB = 1 << 20;

    // ---- phase A layout ----
    unsigned short* out0_bf = (unsigned short*)(wsb);             // 32MB [0,32)
    unsigned short* xbf     = (unsigned short*)(wsb + 32 * MB);   // 32MB [32,64)
    float*          wbuf    = (float*)(wsb + 64 * MB);            // 16MB [64,80)
    unsigned short* t1_bf   = (unsigned short*)(wsb + 80 * MB);   //  8MB [80,88)
    unsigned short* WinT    = (unsigned short*)(wsb + 88 * MB);   //  2MB
    unsigned short* Wa1T    = (unsigned short*)(wsb + 90 * MB);   // .5MB
    unsigned short* Wa2T    = (unsigned short*)(wsb + 90 * MB + 512 * 1024);
    float*          cs_part = (float*)(wsb + 91 * MB);            //  2MB
    float*          colst   = (float*)(wsb + 95 * MB);            // 16KB

    // step-6 scratch (reuses dead phase-A regions; all < 95MB high-water)
    unsigned short* out0T   = (unsigned short*)(wsb + 32 * MB);   // 32MB (xbf dead)
    unsigned short* wT      = (unsigned short*)(wsb + 80 * MB);   //  8MB (t1_bf dead)
    float*          part6   = (float*)(wsb + 64 * MB);            // 16MB (wbuf dead after wT)

    // ---- phase B layout ----
    unsigned short* unorm_bf  = (unsigned short*)(wsb);           //  4MB [0,4)
    float*          xdbc_part = (float*)(wsb + 4 * MB);           //  4MB [4,8)
    float*          dtbuf     = (float*)(wsb + 8 * MB);           // 16MB [8,24)
    unsigned short* ybf       = (unsigned short*)(wsb + 24 * MB); //  8MB [24,32)
    float*          xz        = (float*)(wsb + 32 * MB);          // 32MB [32,64)
    float*          xh        = (float*)(wsb + 64 * MB);          // 16MB [64,80)
    unsigned short* wprojT    = (unsigned short*)(wsb + 80 * MB); //  8MB [80,88)
    unsigned short* oprojT    = (unsigned short*)(wsb + 88 * MB); //  4MB [88,92)
    float*          xdbc      = (float*)(wsb + 92 * MB);          //  1MB [92,93)

    dim3 blk(16, 16);
    const int L = LATC;
    const int M1 = BB * SS;   // 16384
    const int ML = BB * L;    // 2048

    // 0) convert x -> bf16; transpose weights -> bf16 [N][K]
    cvt_bf16<<<dim3((size_t)M1 * D_IN / 2048), dim3(256), 0, stream>>>(x, xbf);
    transp_bf<<<dim3(D_OUTC / 32, D_IN / 32), dim3(256), 0, stream>>>(W_in, WinT, D_IN, D_OUTC, 0, 0);
    transp_bf<<<dim3(LATC / 32, D_OUTC / 32), dim3(256), 0, stream>>>(Wa1, Wa1T, D_OUTC, LATC, 0, 0);
    transp_bf<<<dim3(LATC / 32, LATC / 32), dim3(256), 0, stream>>>(Wa2, Wa2T, LATC, LATC, 0, 0);

    // 1) out0_bf = x @ W_in + b_in   (bf16 out only)
    gemm16<<<dim3(D_OUTC / 128, M1 / 128), dim3(256), 0, stream>>>(
        xbf, D_IN, WinT, D_IN, b_in, (float*)nullptr, 0, out0_bf, D_OUTC,
        M1, D_OUTC, D_IN, 0, 0, 1, 0, 0, 0, 0);

    // 2) t1_bf = silu(out0 @ Wa1 + ba1)
    gemm16<<<dim3(LATC / 128, M1 / 128), dim3(256), 0, stream>>>(
        out0_bf, D_OUTC, Wa1T, D_OUTC, ba1, (float*)nullptr, 0, t1_bf, LATC,
        M1, LATC, D_OUTC, 1, 0, 1, 0, 0, 0, 0);

    // 3) wbuf = t1 @ Wa2 + ba2   (fp32 out for softmax path)
    gemm16<<<dim3(LATC / 128, M1 / 128), dim3(256), 0, stream>>>(
        t1_bf, LATC, Wa2T, LATC, ba2, wbuf, LATC, (unsigned short*)nullptr, 0,
        M1, LATC, LATC, 0, 0, 1, 0, 0, 0, 0);

    // 4/5) softmax mix
    colstats_part_kernel<<<dim3(BB * NCH), dim3(256), 0, stream>>>(wbuf, cs_part);
    colstats_merge_kernel<<<dim3(BB * LATC / 256), dim3(256), 0, stream>>>(cs_part, colst);
    softmix_kernel<<<dim3(BB * SS), dim3(256), 0, stream>>>(wbuf, colst);

    // 6) latout[b] = weights[b]^T @ out0[b] — transposes + split-K=2 gemm16 + merge
    transp16<<<dim3(D_OUTC / 32, SS / 32, BB), dim3(256), 0, stream>>>(
        out0_bf, out0T, SS, D_OUTC, (long)SS * D_OUTC, (long)D_OUTC * SS);
    transp_bf<<<dim3(LATC / 32, SS / 32, BB), dim3(256), 0, stream>>>(
        wbuf, wT, SS, LATC, (long)SS * LATC, (long)LATC * SS);
    gemm16<<<dim3(D_OUTC / 128, LATC / 128, BB * 2), dim3(256), 0, stream>>>(
        wT, SS, out0T, SS, (const float*)nullptr,
        part6, D_OUTC, (unsigned short*)nullptr, 0,
        LATC, D_OUTC, SS / 2, 0, 0,
        2, (long)LATC * SS, (long)D_OUTC * SS, (long)LATC * D_OUTC,
        (long)BB * LATC * D_OUTC);
    merge2_kernel<<<dim3(BB * LATC * D_OUTC / 256), dim3(256), 0, stream>>>(
        part6, latout, BB * LATC * D_OUTC);

    // 7) two mamba blocks
    for (int i = 0; i < 2; i++) {
        const float* in_wi = in_w + (size_t)i * D_OUTC * 2 * DINNER;
        const float* cwi = conv_w + (size_t)i * DINNER * DCONV;
        const float* cbi = conv_b + (size_t)i * DINNER;
        const float* xwi = x_w + (size_t)i * DINNER * (DTRANK + 2 * NSTATE);
        const float* dtwi = dt_w + (size_t)i * DTRANK * DINNER;
        const float* dtbi = dt_b + (size_t)i * DINNER;
        const float* Ali = A_log + (size_t)i * DINNER * NSTATE;
        const float* Dpi = Dp + (size_t)i * DINNER;
        const float* owi = out_w + (size_t)i * DINNER * D_OUTC;
        const float* gi = gamma + (size_t)i * D_OUTC;

        // weight transposes for this block
        transp_bf<<<dim3(2 * DINNER / 32, D_OUTC / 32), dim3(256), 0, stream>>>(
            in_wi, wprojT, D_OUTC, 2 * DINNER, 0, 0);
        transp_bf<<<dim3(D_OUTC / 32, DINNER / 32), dim3(256), 0, stream>>>(
            owi, oprojT, DINNER, D_OUTC, 0, 0);

        // a) RMSNorm (bf16 out)
        rmsnorm_kernel<<<dim3(ML), dim3(256), 0, stream>>>(latout, gi, unorm_bf);

        // b) xz = unorm @ in_proj_w[i]   [2048,4096,1024]  (fp32 out)
        gemm16<<<dim3(2 * DINNER / 128, ML / 128), dim3(256), 0, stream>>>(
            unorm_bf, D_OUTC, wprojT, D_OUTC, (const float*)nullptr,
            xz, 2 * DINNER, (unsigned short*)nullptr, 0,
            ML, 2 * DINNER, D_OUTC, 0, 0, 1, 0, 0, 0, 0);

        // c) xh = silu(causal_conv(xz[:, :DINNER]) + cb)
        conv_silu_kernel<<<dim3(BB * L * DINNER / 256), dim3(256), 0, stream>>>(xz, cwi, cbi, xh, L);

        // d) xdbc = xh @ x_proj_w[i]   (fp32, split-K x4)
        gemm_kernel<<<dim3(128 / 64, ML / 64, 4), blk, 0, stream>>>(
            xh, DINNER, 512, xwi, 128, (long)512 * 128, (const float*)nullptr,
            xdbc_part, 128, (long)ML * 128, ML, 128, 512, 0, 0, 0);
        merge4_kernel<<<dim3(ML * 128 / 256), dim3(256), 0, stream>>>(
            xdbc_part, xdbc, ML * 128);

        // e) dt = softplus(xdbc[:, :64] @ dt_proj_w[i] + dt_b[i])  (fp32)
        gemm_kernel<<<dim3(DINNER / 64, ML / 64, 1), blk, 0, stream>>>(
            xdbc, 128, 0, dtwi, DINNER, 0, dtbi, dtbuf, DINNER, 0, ML, DINNER, DTRANK, 0, 2, 0);

        // f) selective scan (8-way split + 4-deep pipeline) -> ybf (bf16)
        scan_kernel<<<dim3(BB * DINNER * 8 / 256), dim3(256), 0, stream>>>(
            dtbuf, xh, xz, xdbc, Ali, Dpi, ybf, L);

        // g) latout += y @ out_proj_w[i]
        gemm16<<<dim3(D_OUTC / 128, ML / 128), dim3(256), 0, stream>>>(
            ybf, DINNER, oprojT, DINNER, (const float*)nullptr,
            latout, D_OUTC, (unsigned short*)nullptr, 0,
            ML, D_OUTC, DINNER, 0, 1, 1, 0, 0, 0, 0);
    }
}

// Round 13
// 978.775 us; speedup vs baseline: 1.0300x; 1.0115x over previous
//
#include <hip/hip_runtime.h>
#include <math.h>
#include <stdint.h>

#define BB 8
#define SS 2048
#define D_IN 1024
#define D_OUTC 1024
#define LATC 256
#define NSTATE 32
#define DINNER 2048
#define DCONV 4
#define DTRANK 64
#define NCH 32   // colstats time-chunks

__device__ __forceinline__ float silu_f(float v) { return v * (1.f / (1.f + __expf(-v))); }
__device__ __forceinline__ float softplus_f(float v) {
    return fmaxf(v, 0.f) + log1pf(__expf(-fabsf(v)));
}

typedef short short8 __attribute__((ext_vector_type(8)));
typedef float f32x4 __attribute__((ext_vector_type(4)));

__device__ __forceinline__ unsigned short f2bf(float f) {
    unsigned u = __builtin_bit_cast(unsigned, f);
    u += 0x7FFFu + ((u >> 16) & 1u);          // round-to-nearest-even
    return (unsigned short)(u >> 16);
}
__device__ __forceinline__ int pack2(float a, float b) {
    return (int)((unsigned)f2bf(a) | ((unsigned)f2bf(b) << 16));
}

// async global->LDS, 16B per lane. LDS dest = wave-uniform base + lane*16.
typedef const __attribute__((address_space(1))) unsigned int* gas_ptr;
typedef __attribute__((address_space(3))) unsigned int* las_ptr;
__device__ __forceinline__ void gload16(const void* g, void* l) {
    __builtin_amdgcn_global_load_lds(
        reinterpret_cast<gas_ptr>(reinterpret_cast<uintptr_t>(g)),
        reinterpret_cast<las_ptr>(reinterpret_cast<uintptr_t>(l)),
        16, 0, 0);
}

// ---------------------------------------------------------------------------
// Tiled transpose + fp32->bf16 convert: src [K][N] fp32 -> dst [N][K] bf16.
// Optional batch via blockIdx.z with element strides zsrc/zdst.
// ---------------------------------------------------------------------------
__global__ __launch_bounds__(256) void transp_bf(const float* __restrict__ src,
                                                 unsigned short* __restrict__ dst,
                                                 int K, int N, long zsrc, long zdst)
{
    __shared__ float tile[32][33];
    src += (size_t)blockIdx.z * zsrc;
    dst += (size_t)blockIdx.z * zdst;
    const int n0 = blockIdx.x * 32;
    const int k0 = blockIdx.y * 32;
    const int x = threadIdx.x & 31;
    const int y = threadIdx.x >> 5;   // 0..7
#pragma unroll
    for (int j = 0; j < 4; j++)
        tile[y + 8 * j][x] = src[(size_t)(k0 + y + 8 * j) * N + n0 + x];
    __syncthreads();
#pragma unroll
    for (int j = 0; j < 4; j++)
        dst[(size_t)(n0 + y + 8 * j) * K + k0 + x] = f2bf(tile[x][y + 8 * j]);
}

// Tiled bf16 -> bf16 transpose: src [K][N] -> dst [N][K], batched via z.
__global__ __launch_bounds__(256) void transp16(const unsigned short* __restrict__ src,
                                                unsigned short* __restrict__ dst,
                                                int K, int N, long zsrc, long zdst)
{
    __shared__ unsigned short tile[32][33];
    src += (size_t)blockIdx.z * zsrc;
    dst += (size_t)blockIdx.z * zdst;
    const int n0 = blockIdx.x * 32;
    const int k0 = blockIdx.y * 32;
    const int x = threadIdx.x & 31;
    const int y = threadIdx.x >> 5;
#pragma unroll
    for (int j = 0; j < 4; j++)
        tile[y + 8 * j][x] = src[(size_t)(k0 + y + 8 * j) * N + n0 + x];
    __syncthreads();
#pragma unroll
    for (int j = 0; j < 4; j++)
        dst[(size_t)(n0 + y + 8 * j) * K + k0 + x] = tile[x][y + 8 * j];
}

// elementwise fp32 -> bf16 (8 elems/thread); n must be multiple of 2048
__global__ __launch_bounds__(256) void cvt_bf16(const float* __restrict__ in,
                                                unsigned short* __restrict__ out)
{
    size_t i = ((size_t)blockIdx.x * 256 + threadIdx.x) * 8;
    float4 a = *(const float4*)(in + i);
    float4 b = *(const float4*)(in + i + 4);
    int4 w;
    w.x = pack2(a.x, a.y); w.y = pack2(a.z, a.w);
    w.z = pack2(b.x, b.y); w.w = pack2(b.z, b.w);
    *(int4*)(out + i) = w;
}

// ---------------------------------------------------------------------------
// bf16 MFMA GEMM: async-staged, 3-buffer depth-2 pipeline with COUNTED vmcnt
// (T4: never drain to 0 mid-loop), XCD-bijective block swizzle.
// ---------------------------------------------------------------------------
__global__ __launch_bounds__(256) void gemm16(
    const unsigned short* __restrict__ A, int lda,
    const unsigned short* __restrict__ BT, int ldb,
    const float* __restrict__ bias,
    float* __restrict__ C, int ldc,
    unsigned short* __restrict__ C16, int ldc16,
    int M, int N, int K, int act, int accum,
    int kspl, long zA, long zB, long zC, long zK)
{
    __shared__ __align__(16) unsigned short As[3][128 * 32];
    __shared__ __align__(16) unsigned short Bs[3][128 * 32];

    const int bz = blockIdx.z / kspl;
    const int ks = blockIdx.z % kspl;
    A += (size_t)bz * zA + (size_t)ks * (size_t)K;
    BT += (size_t)bz * zB + (size_t)ks * (size_t)K;
    if (C) C += (size_t)bz * zC + (size_t)ks * zK;

    const int tid = threadIdx.x;
    const int lane = tid & 63;
    const int wave = tid >> 6;   // 0..3
    const int wr = wave >> 1;    // wave row 0..1
    const int wc = wave & 1;     // wave col 0..1
    const int quad = lane >> 4;  // 0..3
    const int l16 = lane & 15;

    // XCD-aware bijective swizzle (T1, m204 formula) on the xy-plane
    const int nbx = gridDim.x;
    const int nwg = nbx * gridDim.y;
    const int orig = blockIdx.y * nbx + blockIdx.x;
    const int q = nwg >> 3, r = nwg & 7;
    const int xcd = orig & 7, lid = orig >> 3;
    const int swz = (xcd < r) ? (xcd * (q + 1) + lid)
                              : (r * (q + 1) + (xcd - r) * q + lid);
    const int m0 = (swz / nbx) * 128;
    const int n0 = (swz % nbx) * 128;

    const int srow4 = lane >> 2;   // 0..15
    const int sphys = lane & 3;    // physical 16B slot within 64B row

    f32x4 acc[4][4];
#pragma unroll
    for (int i = 0; i < 4; i++)
#pragma unroll
        for (int j = 0; j < 4; j++) acc[i][j] = (f32x4){0.f, 0.f, 0.f, 0.f};

    const int nt = K >> 5;

    auto STAGE = [&](int buf, int t) {
        const int k0 = t << 5;
#pragma unroll
        for (int i = 0; i < 2; i++) {
            const int rbase = (wave << 5) + (i << 4);
            const int rr = rbase + srow4;                       // 0..127
            const int ls = sphys ^ ((rr >> 1) & 3);             // logical slot
            gload16(A + (size_t)(m0 + rr) * lda + (k0 + (ls << 3)), &As[buf][rbase << 5]);
            gload16(BT + (size_t)(n0 + rr) * ldb + (k0 + (ls << 3)), &Bs[buf][rbase << 5]);
        }
    };

    // prologue: stage tiles 0 and 1; wait for tile 0 only (counted)
    STAGE(0, 0);
    if (nt > 1) {
        STAGE(1, 1);
        asm volatile("s_waitcnt vmcnt(4)" ::: "memory");
    } else {
        asm volatile("s_waitcnt vmcnt(0)" ::: "memory");
    }
    __syncthreads();

    int cur = 0;
    for (int t = 0; t < nt; ++t) {
        // issue tile t+2 into buffer (t+2)%3 — two stages in flight
        int sb = cur + 2; if (sb >= 3) sb -= 3;
        if (t + 2 < nt) STAGE(sb, t + 2);

        short8 af[4], bfr[4];
#pragma unroll
        for (int i = 0; i < 4; i++) {
            const int ar = (wr << 6) + (i << 4) + l16;
            af[i] = *(const short8*)&As[cur][(ar << 5) + ((quad ^ ((ar >> 1) & 3)) << 3)];
            const int br = (wc << 6) + (i << 4) + l16;
            bfr[i] = *(const short8*)&Bs[cur][(br << 5) + ((quad ^ ((br >> 1) & 3)) << 3)];
        }
#pragma unroll
        for (int i = 0; i < 4; i++)
#pragma unroll
            for (int j = 0; j < 4; j++)
                acc[i][j] = __builtin_amdgcn_mfma_f32_16x16x32_bf16(af[i], bfr[j], acc[i][j], 0, 0, 0);

        // need tile t+1 landed before next iter; newest stage (t+2) may fly
        if (t + 2 < nt) asm volatile("s_waitcnt vmcnt(4)" ::: "memory");
        else            asm volatile("s_waitcnt vmcnt(0)" ::: "memory");
        __syncthreads();
        cur = (cur == 2) ? 0 : cur + 1;
    }

    // epilogue: D mapping col = lane&15, row = quad*4 + reg
#pragma unroll
    for (int j = 0; j < 4; j++) {
        int gn = n0 + wc * 64 + j * 16 + l16;
        float bv = bias ? bias[gn] : 0.f;
#pragma unroll
        for (int i = 0; i < 4; i++) {
#pragma unroll
            for (int r2 = 0; r2 < 4; r2++) {
                int gm = m0 + wr * 64 + i * 16 + quad * 4 + r2;
                float v = acc[i][j][r2] + bv;
                if (act == 1) v = silu_f(v);
                else if (act == 2) v = softplus_f(v);
                if (C) {
                    size_t ci = (size_t)gm * ldc + gn;
                    if (accum) C[ci] += v;
                    else C[ci] = v;
                }
                if (C16) C16[(size_t)gm * ldc16 + gn] = f2bf(v);
            }
        }
    }
}

// ---------------------------------------------------------------------------
// fp32 SIMT GEMM (small / accuracy-sensitive GEMMs: x_proj, dt_proj)
// ---------------------------------------------------------------------------
__global__ __launch_bounds__(256) void gemm_kernel(
    const float* __restrict__ A, int lda, long strideA,
    const float* __restrict__ B, int ldb, long strideB,
    const float* __restrict__ bias,
    float* __restrict__ C, int ldc, long strideC,
    int M, int N, int K, int transA, int act, int accum)
{
    __shared__ float As[16][65];
    __shared__ float Bsh[16][64];

    const int bz = blockIdx.z;
    const float* Ab = A + (size_t)bz * strideA;
    const float* Bb = B + (size_t)bz * strideB;
    float* Cb = C + (size_t)bz * strideC;

    const int tx = threadIdx.x;
    const int ty = threadIdx.y;
    const int tid = ty * 16 + tx;
    const int m0 = blockIdx.y * 64;
    const int n0 = blockIdx.x * 64;

    float acc[4][4];
#pragma unroll
    for (int i = 0; i < 4; i++)
#pragma unroll
        for (int j = 0; j < 4; j++) acc[i][j] = 0.f;

    for (int k0 = 0; k0 < K; k0 += 16) {
        if (!transA) {
            int row = tid >> 2;
            int kc = (tid & 3) * 4;
            int gm = m0 + row;
#pragma unroll
            for (int j = 0; j < 4; j++) {
                int gk = k0 + kc + j;
                As[kc + j][row] = (gm < M && gk < K) ? Ab[(size_t)gm * lda + gk] : 0.f;
            }
        } else {
            int krow = tid >> 4;
            int mc = (tid & 15) * 4;
            int gk = k0 + krow;
#pragma unroll
            for (int j = 0; j < 4; j++) {
                int gm = m0 + mc + j;
                As[krow][mc + j] = (gm < M && gk < K) ? Ab[(size_t)gk * lda + gm] : 0.f;
            }
        }
        {
            int krow = tid >> 4;
            int nc = (tid & 15) * 4;
            int gk = k0 + krow;
#pragma unroll
            for (int j = 0; j < 4; j++) {
                int gn = n0 + nc + j;
                Bsh[krow][nc + j] = (gk < K && gn < N) ? Bb[(size_t)gk * ldb + gn] : 0.f;
            }
        }
        __syncthreads();
#pragma unroll
        for (int k = 0; k < 16; k++) {
            float a[4], bv[4];
#pragma unroll
            for (int i = 0; i < 4; i++) a[i] = As[k][ty * 4 + i];
#pragma unroll
            for (int j = 0; j < 4; j++) bv[j] = Bsh[k][tx * 4 + j];
#pragma unroll
            for (int i = 0; i < 4; i++)
#pragma unroll
                for (int j = 0; j < 4; j++) acc[i][j] += a[i] * bv[j];
        }
        __syncthreads();
    }

#pragma unroll
    for (int i = 0; i < 4; i++) {
        int gm = m0 + ty * 4 + i;
        if (gm >= M) continue;
#pragma unroll
        for (int j = 0; j < 4; j++) {
            int gn = n0 + tx * 4 + j;
            if (gn >= N) continue;
            float v = acc[i][j];
            if (bias) v += bias[gn];
            if (act == 1) v = silu_f(v);
            else if (act == 2) v = softplus_f(v);
            size_t ci = (size_t)gm * ldc + gn;
            if (accum) Cb[ci] += v;
            else Cb[ci] = v;
        }
    }
}

// sum 4 split-K partials
__global__ __launch_bounds__(256) void merge4_kernel(const float* __restrict__ part,
                                                     float* __restrict__ out, int n)
{
    int i = blockIdx.x * 256 + threadIdx.x;
    out[i] = part[i] + part[i + n] + part[i + 2 * n] + part[i + 3 * n];
}

// sum 2 split-K partials
__global__ __launch_bounds__(256) void merge2_kernel(const float* __restrict__ part,
                                                     float* __restrict__ out, int n)
{
    int i = blockIdx.x * 256 + threadIdx.x;
    out[i] = part[i] + part[i + n];
}

// ---------------------------------------------------------------------------
// column softmax stats, 2-phase
// ---------------------------------------------------------------------------
__global__ __launch_bounds__(256) void colstats_part_kernel(const float* __restrict__ w,
                                                            float* __restrict__ part)
{
    int b = blockIdx.x / NCH;
    int ch = blockIdx.x % NCH;
    int l = threadIdx.x;
    const float* base = w + ((size_t)b * SS + (size_t)ch * (SS / NCH)) * LATC + l;
    float m = -1e30f, s = 0.f;
    for (int t = 0; t < SS / NCH; t++) {
        float v = base[(size_t)t * LATC];
        float nm = fmaxf(m, v);
        s = s * __expf(m - nm) + __expf(v - nm);
        m = nm;
    }
    float2* p = (float2*)part;
    p[(size_t)(b * LATC + l) * NCH + ch] = make_float2(m, s);
}

__global__ __launch_bounds__(256) void colstats_merge_kernel(const float* __restrict__ part,
                                                             float* __restrict__ colst)
{
    int idx = blockIdx.x * 256 + threadIdx.x;   // 0 .. BB*LATC-1
    const float2* p = (const float2*)part + (size_t)idx * NCH;
    float m = -1e30f, s = 0.f;
#pragma unroll 4
    for (int c = 0; c < NCH; c++) {
        float2 v = p[c];
        float nm = fmaxf(m, v.x);
        s = s * __expf(m - nm) + v.y * __expf(v.x - nm);
        m = nm;
    }
    colst[idx * 2] = m;
    colst[idx * 2 + 1] = s;
}

__global__ __launch_bounds__(256) void softmix_kernel(float* __restrict__ w,
                                                      const float* __restrict__ colst)
{
    int bs = blockIdx.x;
    int b = bs / SS;
    int l = threadIdx.x;
    float* row = w + (size_t)bs * LATC;
    float v = row[l];

    __shared__ float sm[256];
    sm[l] = v;
    __syncthreads();
    for (int st = 128; st > 0; st >>= 1) {
        if (l < st) sm[l] = fmaxf(sm[l], sm[l + st]);
        __syncthreads();
    }
    float rmax = sm[0];
    __syncthreads();
    float e = __expf(v - rmax);
    sm[l] = e;
    __syncthreads();
    for (int st = 128; st > 0; st >>= 1) {
        if (l < st) sm[l] += sm[l + st];
        __syncthreads();
    }
    float rsum = sm[0];

    float w1 = e / rsum * ((float)LATC / (float)SS);
    float cm = colst[(b * LATC + l) * 2];
    float cs = colst[(b * LATC + l) * 2 + 1];
    float w2 = __expf(v - cm) / cs;
    row[l] = 0.5f * (w1 + w2);
}

// RMSNorm, bf16 output (consumed only as GEMM-A)
__global__ __launch_bounds__(256) void rmsnorm_kernel(const float* __restrict__ x,
                                                      const float* __restrict__ gamma,
                                                      unsigned short* __restrict__ out)
{
    int row = blockIdx.x;
    const float* xr = x + (size_t)row * D_OUTC;
    float v[4];
    float ss = 0.f;
#pragma unroll
    for (int i = 0; i < 4; i++) {
        v[i] = xr[threadIdx.x + i * 256];
        ss += v[i] * v[i];
    }
#pragma unroll
    for (int off = 32; off >= 1; off >>= 1) ss += __shfl_xor(ss, off, 64);
    __shared__ float sred[4];
    int wave = threadIdx.x >> 6;
    if ((threadIdx.x & 63) == 0) sred[wave] = ss;
    __syncthreads();
    float tot = sred[0] + sred[1] + sred[2] + sred[3];
    float inv = 32.0f / fmaxf(sqrtf(tot), 1e-12f);
    unsigned short* outr = out + (size_t)row * D_OUTC;
#pragma unroll
    for (int i = 0; i < 4; i++) {
        int d = threadIdx.x + i * 256;
        outr[d] = f2bf(v[i] * inv * gamma[d]);
    }
}

__global__ __launch_bounds__(256) void conv_silu_kernel(const float* __restrict__ xz,
                                                        const float* __restrict__ cw,
                                                        const float* __restrict__ cb,
                                                        float* __restrict__ xh, int L)
{
    int idx = blockIdx.x * 256 + threadIdx.x;
    int c = idx % DINNER;
    int bl = idx / DINNER;
    int l = bl % L;
    int b = bl / L;
    float acc = cb[c];
#pragma unroll
    for (int j = 0; j < DCONV; j++) {
        int ls = l - (DCONV - 1) + j;
        if (ls >= 0)
            acc += xz[((size_t)(b * L + ls)) * (2 * DINNER) + c] * cw[c * DCONV + j];
    }
    xh[idx] = silu_f(acc);
}

// ---------------------------------------------------------------------------
// selective scan, 8-way state-split + 8-deep input pipeline (SCH 4->8).
// 32 chunks of 8 steps; the c-loop is unrolled by 2 with A/B queue role swap
// (ping-pong) so there are NO register rotate moves. Prefetch of chunk c+1 is
// issued before computing chunk c -> ~1000cy compute fully covers the L3/HBM
// round trip that SCH=4's ~500cy chunk could not. All queue indices are
// compile-time constants (rule #20).
// ---------------------------------------------------------------------------
#define SCH 8
__global__ __launch_bounds__(256) void scan_kernel(const float* __restrict__ dty,
                                                   const float* __restrict__ xh,
                                                   const float* __restrict__ xz,
                                                   const float* __restrict__ xdbc,
                                                   const float* __restrict__ A_log,
                                                   const float* __restrict__ Dp,
                                                   unsigned short* __restrict__ ybf,
                                                   int L)
{
    const int t = threadIdx.x;
    const int g = t & 7;          // state group: states g*4 .. g*4+3
    const int dloc = t >> 3;      // 0..31
    const int b = blockIdx.x >> 6;
    const int d = ((blockIdx.x & 63) << 5) + dloc;

    float4 Av = *(const float4*)(A_log + (size_t)d * NSTATE + g * 4);
    const float A0 = -__expf(Av.x), A1 = -__expf(Av.y), A2 = -__expf(Av.z), A3 = -__expf(Av.w);
    float h0 = 0.f, h1 = 0.f, h2 = 0.f, h3 = 0.f;
    const float Dd = Dp[d];

    const float* pdt = dty + (size_t)b * L * DINNER + d;
    const float* pxh = xh + (size_t)b * L * DINNER + d;
    const float* pz  = xz + (size_t)b * L * 2 * DINNER + DINNER + d;
    const float* pbc = xdbc + (size_t)b * L * 128 + DTRANK + g * 4;
    unsigned short* pout = ybf + (size_t)b * L * DINNER + d;

    float a_dt[SCH], a_x[SCH], a_z[SCH];
    float4 a_B[SCH], a_C[SCH];
    float n_dt[SCH], n_x[SCH], n_z[SCH];
    float4 n_B[SCH], n_C[SCH];

#define SCAN_PREFETCH(q_dt, q_x, q_z, q_B, q_C, cc)                              \
    _Pragma("unroll")                                                            \
    for (int j = 0; j < SCH; j++) {                                              \
        size_t ll = (size_t)(cc) * SCH + j;                                      \
        q_dt[j] = pdt[ll * DINNER];                                              \
        q_x[j]  = pxh[ll * DINNER];                                              \
        q_z[j]  = pz[ll * 2 * DINNER];                                           \
        q_B[j]  = *(const float4*)(pbc + ll * 128);                              \
        q_C[j]  = *(const float4*)(pbc + ll * 128 + NSTATE);                     \
    }

#define SCAN_COMPUTE(q_dt, q_x, q_z, q_B, q_C, cc)                               \
    _Pragma("unroll")                                                            \
    for (int j = 0; j < SCH; j++) {                                              \
        float dtv = q_dt[j], xv = q_x[j], zv = q_z[j];                           \
        float dtx = dtv * xv;                                                    \
        float e0 = __expf(dtv * A0);                                             \
        float e1 = __expf(dtv * A1);                                             \
        float e2 = __expf(dtv * A2);                                             \
        float e3 = __expf(dtv * A3);                                             \
        h0 = e0 * h0 + dtx * q_B[j].x;                                           \
        h1 = e1 * h1 + dtx * q_B[j].y;                                           \
        h2 = e2 * h2 + dtx * q_B[j].z;                                           \
        h3 = e3 * h3 + dtx * q_B[j].w;                                           \
        float accv = h0 * q_C[j].x + h1 * q_C[j].y + h2 * q_C[j].z + h3 * q_C[j].w; \
        accv += __shfl_xor(accv, 1, 64);                                         \
        accv += __shfl_xor(accv, 2, 64);                                         \
        accv += __shfl_xor(accv, 4, 64);                                         \
        if (g == 0) {                                                            \
            float yv = (accv + Dd * xv) * silu_f(zv);                            \
            pout[((size_t)(cc) * SCH + j) * DINNER] = f2bf(yv);                  \
        }                                                                        \
    }

    const int nchk = L / SCH;   // 32 (even — ping-pong is exact)

    // preload chunk 0 into queue A
    SCAN_PREFETCH(a_dt, a_x, a_z, a_B, a_C, 0)

    for (int c = 0; c < nchk; c += 2) {
        // prefetch chunk c+1 into queue N, compute chunk c from queue A
        SCAN_PREFETCH(n_dt, n_x, n_z, n_B, n_C, c + 1)
        SCAN_COMPUTE(a_dt, a_x, a_z, a_B, a_C, c)
        // prefetch chunk c+2 into queue A, compute chunk c+1 from queue N
        if (c + 2 < nchk) { SCAN_PREFETCH(a_dt, a_x, a_z, a_B, a_C, c + 2) }
        SCAN_COMPUTE(n_dt, n_x, n_z, n_B, n_C, c + 1)
    }
#undef SCAN_PREFETCH
#undef SCAN_COMPUTE
}

// ---------------------------------------------------------------------------

extern "C" void kernel_launch(void* const* d_in, const int* in_sizes, int n_in,
                              void* d_out, int out_size, void* d_ws, size_t ws_size,
                              hipStream_t stream)
{
    const float* x      = (const float*)d_in[0];
    const float* W_in   = (const float*)d_in[1];
    const float* b_in   = (const float*)d_in[2];
    const float* Wa1    = (const float*)d_in[3];
    const float* ba1    = (const float*)d_in[4];
    const float* Wa2    = (const float*)d_in[5];
    const float* ba2    = (const float*)d_in[6];
    const float* gamma  = (const float*)d_in[7];
    const float* in_w   = (const float*)d_in[8];
    const float* conv_w = (const float*)d_in[9];
    const float* conv_b = (const float*)d_in[10];
    const float* x_w    = (const float*)d_in[11];
    const float* dt_w   = (const float*)d_in[12];
    const float* dt_b   = (const float*)d_in[13];
    const float* A_log  = (const float*)d_in[14];
    const float* Dp     = (const float*)d_in[15];
    const float* out_w  = (const float*)d_in[16];
    float* latout = (float*)d_out;

    char* wsb = (char*)d_ws;
    const size_t MB = 1 << 20;

    // ---- phase A layout ----
    unsigned short* out0_bf = (unsigned short*)(wsb);             // 32MB [0,32)
    unsigned short* xbf     = (unsigned short*)(wsb + 32 * MB);   // 32MB [32,64)
    float*          wbuf    = (float*)(wsb + 64 * MB);            // 16MB [64,80)
    unsigned short* t1_bf   = (unsigned short*)(wsb + 80 * MB);   //  8MB [80,88)
    unsigned short* WinT    = (unsigned short*)(wsb + 88 * MB);   //  2MB
    unsigned short* Wa1T    = (unsigned short*)(wsb + 90 * MB);   // .5MB
    unsigned short* Wa2T    = (unsigned short*)(wsb + 90 * MB + 512 * 1024);
    float*          cs_part = (float*)(wsb + 91 * MB);            //  2MB
    float*          colst   = (float*)(wsb + 95 * MB);            // 16KB

    // step-6 scratch (reuses dead phase-A regions; all < 95MB high-water)
    unsigned short* out0T   = (unsigned short*)(wsb + 32 * MB);   // 32MB (xbf dead)
    unsigned short* wT      = (unsigned short*)(wsb + 80 * MB);   //  8MB (t1_bf dead)
    float*          part6   = (float*)(wsb + 64 * MB);            // 16MB (wbuf dead after wT)

    // ---- phase B layout ----
    unsigned short* unorm_bf  = (unsigned short*)(wsb);           //  4MB [0,4)
    float*          xdbc_part = (float*)(wsb + 4 * MB);           //  4MB [4,8)
    float*          dtbuf     = (float*)(wsb + 8 * MB);           // 16MB [8,24)
    unsigned short* ybf       = (unsigned short*)(wsb + 24 * MB); //  8MB [24,32)
    float*          xz        = (float*)(wsb + 32 * MB);          // 32MB [32,64)
    float*          xh        = (float*)(wsb + 64 * MB);          // 16MB [64,80)
    unsigned short* wprojT    = (unsigned short*)(wsb + 80 * MB); //  8MB [80,88)
    unsigned short* oprojT    = (unsigned short*)(wsb + 88 * MB); //  4MB [88,92)
    float*          xdbc      = (float*)(wsb + 92 * MB);          //  1MB [92,93)

    dim3 blk(16, 16);
    const int L = LATC;
    const int M1 = BB * SS;   // 16384
    const int ML = BB * L;    // 2048

    // 0) convert x -> bf16; transpose weights -> bf16 [N][K]
    cvt_bf16<<<dim3((size_t)M1 * D_IN / 2048), dim3(256), 0, stream>>>(x, xbf);
    transp_bf<<<dim3(D_OUTC / 32, D_IN / 32), dim3(256), 0, stream>>>(W_in, WinT, D_IN, D_OUTC, 0, 0);
    transp_bf<<<dim3(LATC / 32, D_OUTC / 32), dim3(256), 0, stream>>>(Wa1, Wa1T, D_OUTC, LATC, 0, 0);
    transp_bf<<<dim3(LATC / 32, LATC / 32), dim3(256), 0, stream>>>(Wa2, Wa2T, LATC, LATC, 0, 0);

    // 1) out0_bf = x @ W_in + b_in   (bf16 out only)
    gemm16<<<dim3(D_OUTC / 128, M1 / 128), dim3(256), 0, stream>>>(
        xbf, D_IN, WinT, D_IN, b_in, (float*)nullptr, 0, out0_bf, D_OUTC,
        M1, D_OUTC, D_IN, 0, 0, 1, 0, 0, 0, 0);

    // 2) t1_bf = silu(out0 @ Wa1 + ba1)
    gemm16<<<dim3(LATC / 128, M1 / 128), dim3(256), 0, stream>>>(
        out0_bf, D_OUTC, Wa1T, D_OUTC, ba1, (float*)nullptr, 0, t1_bf, LATC,
        M1, LATC, D_OUTC, 1, 0, 1, 0, 0, 0, 0);

    // 3) wbuf = t1 @ Wa2 + ba2   (fp32 out for softmax path)
    gemm16<<<dim3(LATC / 128, M1 / 128), dim3(256), 0, stream>>>(
        t1_bf, LATC, Wa2T, LATC, ba2, wbuf, LATC, (unsigned short*)nullptr, 0,
        M1, LATC, LATC, 0, 0, 1, 0, 0, 0, 0);

    // 4/5) softmax mix
    colstats_part_kernel<<<dim3(BB * NCH), dim3(256), 0, stream>>>(wbuf, cs_part);
    colstats_merge_kernel<<<dim3(BB * LATC / 256), dim3(256), 0, stream>>>(cs_part, colst);
    softmix_kernel<<<dim3(BB * SS), dim3(256), 0, stream>>>(wbuf, colst);

    // 6) latout[b] = weights[b]^T @ out0[b] — transposes + split-K=2 gemm16 + merge
    transp16<<<dim3(D_OUTC / 32, SS / 32, BB), dim3(256), 0, stream>>>(
        out0_bf, out0T, SS, D_OUTC, (long)SS * D_OUTC, (long)D_OUTC * SS);
    transp_bf<<<dim3(LATC / 32, SS / 32, BB), dim3(256), 0, stream>>>(
        wbuf, wT, SS, LATC, (long)SS * LATC, (long)LATC * SS);
    gemm16<<<dim3(D_OUTC / 128, LATC / 128, BB * 2), dim3(256), 0, stream>>>(
        wT, SS, out0T, SS, (const float*)nullptr,
        part6, D_OUTC, (unsigned short*)nullptr, 0,
        LATC, D_OUTC, SS / 2, 0, 0,
        2, (long)LATC * SS, (long)D_OUTC * SS, (long)LATC * D_OUTC,
        (long)BB * LATC * D_OUTC);
    merge2_kernel<<<dim3(BB * LATC * D_OUTC / 256), dim3(256), 0, stream>>>(
        part6, latout, BB * LATC * D_OUTC);

    // 7) two mamba blocks
    for (int i = 0; i < 2; i++) {
        const float* in_wi = in_w + (size_t)i * D_OUTC * 2 * DINNER;
        const float* cwi = conv_w + (size_t)i * DINNER * DCONV;
        const float* cbi = conv_b + (size_t)i * DINNER;
        const float* xwi = x_w + (size_t)i * DINNER * (DTRANK + 2 * NSTATE);
        const float* dtwi = dt_w + (size_t)i * DTRANK * DINNER;
        const float* dtbi = dt_b + (size_t)i * DINNER;
        const float* Ali = A_log + (size_t)i * DINNER * NSTATE;
        const float* Dpi = Dp + (size_t)i * DINNER;
        const float* owi = out_w + (size_t)i * DINNER * D_OUTC;
        const float* gi = gamma + (size_t)i * D_OUTC;

        // weight transposes for this block
        transp_bf<<<dim3(2 * DINNER / 32, D_OUTC / 32), dim3(256), 0, stream>>>(
            in_wi, wprojT, D_OUTC, 2 * DINNER, 0, 0);
        transp_bf<<<dim3(D_OUTC / 32, DINNER / 32), dim3(256), 0, stream>>>(
            owi, oprojT, DINNER, D_OUTC, 0, 0);

        // a) RMSNorm (bf16 out)
        rmsnorm_kernel<<<dim3(ML), dim3(256), 0, stream>>>(latout, gi, unorm_bf);

        // b) xz = unorm @ in_proj_w[i]   [2048,4096,1024]  (fp32 out)
        gemm16<<<dim3(2 * DINNER / 128, ML / 128), dim3(256), 0, stream>>>(
            unorm_bf, D_OUTC, wprojT, D_OUTC, (const float*)nullptr,
            xz, 2 * DINNER, (unsigned short*)nullptr, 0,
            ML, 2 * DINNER, D_OUTC, 0, 0, 1, 0, 0, 0, 0);

        // c) xh = silu(causal_conv(xz[:, :DINNER]) + cb)
        conv_silu_kernel<<<dim3(BB * L * DINNER / 256), dim3(256), 0, stream>>>(xz, cwi, cbi, xh, L);

        // d) xdbc = xh @ x_proj_w[i]   (fp32, split-K x4)
        gemm_kernel<<<dim3(128 / 64, ML / 64, 4), blk, 0, stream>>>(
            xh, DINNER, 512, xwi, 128, (long)512 * 128, (const float*)nullptr,
            xdbc_part, 128, (long)ML * 128, ML, 128, 512, 0, 0, 0);
        merge4_kernel<<<dim3(ML * 128 / 256), dim3(256), 0, stream>>>(
            xdbc_part, xdbc, ML * 128);

        // e) dt = softplus(xdbc[:, :64] @ dt_proj_w[i] + dt_b[i])  (fp32)
        gemm_kernel<<<dim3(DINNER / 64, ML / 64, 1), blk, 0, stream>>>(
            xdbc, 128, 0, dtwi, DINNER, 0, dtbi, dtbuf, DINNER, 0, ML, DINNER, DTRANK, 0, 2, 0);

        // f) selective scan (8-way split + 8-deep ping-pong pipeline) -> ybf
        scan_kernel<<<dim3(BB * DINNER * 8 / 256), dim3(256), 0, stream>>>(
            dtbuf, xh, xz, xdbc, Ali, Dpi, ybf, L);

        // g) latout += y @ out_proj_w[i]
        gemm16<<<dim3(D_OUTC / 128, ML / 128), dim3(256), 0, stream>>>(
            ybf, DINNER, oprojT, DINNER, (const float*)nullptr,
            latout, D_OUTC, (unsigned short*)nullptr, 0,
            ML, D_OUTC, DINNER, 0, 1, 1, 0, 0, 0, 0);
    }
}